// Round 6
// baseline (310.897 us; speedup 1.0000x reference)
//
#include <hip/hip_runtime.h>
#include <hip/hip_bf16.h>

#define BB 32
#define INP 1024
#define WIDTH 256
#define OUTP 1024
#define NE 8
#define HW 196
#define HH 14
#define EPS 1e-5f

#define S1 (WIDTH * INP)        // 262144
#define S2 (WIDTH * WIDTH * 9)  // 589824
#define S3 (OUTP * WIDTH)       // 262144

typedef __attribute__((ext_vector_type(8))) short bf16x8;
typedef __attribute__((ext_vector_type(4))) float f32x4;
typedef __attribute__((ext_vector_type(8))) unsigned short u16x8;

// Swizzled operand layout: tile = 16 rows x 32 k = 512 bf16 = 1 KB.
// Element (r,k) at lane*8 + (k&7), lane = (r&15) | (((k>>3)&3)<<4).
// A wave's MFMA fragment load = tile_base + lane*16B (contiguous 1 KB).

__device__ __forceinline__ unsigned short f2bf_bits(float f) {
    unsigned u = __float_as_uint(f);
    u += 0x7FFFu + ((u >> 16) & 1u);   // RNE
    return (unsigned short)(u >> 16);
}

#if defined(__has_builtin)
#if __has_builtin(__builtin_amdgcn_global_load_lds)
#define HAVE_GLL 1
#endif
#endif
// Async global->LDS: per-lane 16-B source address g; dest = l + lane*16.
__device__ __forceinline__ void gl2lds(const unsigned short* g, unsigned short* l,
                                       int lane) {
#ifdef HAVE_GLL
    __builtin_amdgcn_global_load_lds(
        (const __attribute__((address_space(1))) unsigned int*)(const void*)g,
        (__attribute__((address_space(3))) unsigned int*)(void*)l, 16, 0, 0);
#else
    *(u16x8*)(l + lane * 8) = *(const u16x8*)g;
#endif
}

// ---------------------------------------------------------------------------
// Fused transpose + mean of x: fp32 NCHW -> swizzled bf16 B-operand
// xb[b][nt=14][kt=32][512] + mean1[b][c]. grid (32, 8).
// ---------------------------------------------------------------------------
__global__ __launch_bounds__(256) void transpose_mean_x(
    const float* __restrict__ x, unsigned short* __restrict__ xb,
    float* __restrict__ mean1) {
    __shared__ float lt[128][17];
    int b = blockIdx.x, c0 = blockIdx.y * 128;
    int t = threadIdx.x, cr = t >> 1, half = t & 1;
    const float* src = x + ((size_t)(b * INP + c0 + cr)) * HW;
    float msum = 0.f;
    int j = t >> 4, nl = t & 15;
    for (int pg = 0; pg < 14; pg++) {
        int p0 = pg * 16 + half * 8;
        float vv[8];
        if (pg < 12) {
            float4 a = *(const float4*)(src + p0);
            float4 c = *(const float4*)(src + p0 + 4);
            vv[0] = a.x; vv[1] = a.y; vv[2] = a.z; vv[3] = a.w;
            vv[4] = c.x; vv[5] = c.y; vv[6] = c.z; vv[7] = c.w;
        } else {
#pragma unroll
            for (int i = 0; i < 8; i++) {
                int p = p0 + i;
                vv[i] = (p < HW) ? src[p] : 0.f;
            }
        }
#pragma unroll
        for (int i = 0; i < 8; i++) { msum += vv[i]; lt[cr][half * 8 + i] = vv[i]; }
        __syncthreads();
        unsigned short pk[8];
#pragma unroll
        for (int i = 0; i < 8; i++) pk[i] = f2bf_bits(lt[j * 8 + i][nl]);
        size_t tile = ((size_t)b * 14 + pg) * 32 + (size_t)(blockIdx.y * 4 + (j >> 2));
        int lane = nl | ((j & 3) << 4);
        *(u16x8*)(xb + tile * 512 + lane * 8) = *(u16x8*)pk;
        __syncthreads();
    }
    float other = __shfl_xor(msum, 1, 64);
    if (half == 0) mean1[b * INP + c0 + cr] = (msum + other) * (1.0f / (float)HW);
}

// ---------------------------------------------------------------------------
// Routing: rw[b,e] = sigmoid(scale * (vec[b,:] @ W) + bias). grid = B.
// ---------------------------------------------------------------------------
__global__ __launch_bounds__(256) void route_kernel(const float* __restrict__ mean,
                                                    const float* __restrict__ W,
                                                    const float* __restrict__ bias,
                                                    float* __restrict__ rw, int C,
                                                    float scale) {
    __shared__ float red[NE * 256];
    int b = blockIdx.x, t = threadIdx.x;
    float part[NE];
#pragma unroll
    for (int e = 0; e < NE; e++) part[e] = 0.f;
    for (int c = t; c < C; c += 256) {
        float m = mean[b * C + c];
#pragma unroll
        for (int e = 0; e < NE; e++) part[e] += m * W[c * NE + e];
    }
#pragma unroll
    for (int e = 0; e < NE; e++) red[e * 256 + t] = part[e];
    __syncthreads();
    for (int st = 128; st > 0; st >>= 1) {
        if (t < st) {
#pragma unroll
            for (int e = 0; e < NE; e++) red[e * 256 + t] += red[e * 256 + t + st];
        }
        __syncthreads();
    }
    if (t < NE) {
        float z = red[t * 256] * scale + bias[t];
        rw[b * NE + t] = 1.0f / (1.0f + expf(-z));
    }
}

// ---------------------------------------------------------------------------
// Combine (contiguous-k experts, w1/w3): coalesced tile writes.
// Wave = one swizzled tile: lane = (m&15) | (k8&3)<<4; block = 4 k-tiles of
// one m-tile; grid = (Mt*Kt/4, 4 sample groups). Each wave stores 1 KB
// contiguous per sample (8 samples per group).
// ---------------------------------------------------------------------------
__global__ __launch_bounds__(256) void combine_cont(
    const float* __restrict__ w, const float* __restrict__ rw,
    unsigned short* __restrict__ cw, int S, int Mt, int Kt) {
    __shared__ float srw[64];
    int tid = threadIdx.x, wv = tid >> 6, lane = tid & 63, ml = lane & 15, k8l = lane >> 4;
    int g = blockIdx.y;
    if (tid < 64) srw[tid] = rw[g * 64 + tid];
    __syncthreads();
    int kq = Kt >> 2;
    int mt = blockIdx.x / kq, kt = (blockIdx.x - mt * kq) * 4 + wv;
    int K = Kt * 32;
    const float* src = w + (size_t)(mt * 16 + ml) * K + kt * 32 + k8l * 8;
    float v[NE][8];
#pragma unroll
    for (int e = 0; e < NE; e++) {
        float4 a = *(const float4*)(src + (size_t)e * S);
        float4 c = *(const float4*)(src + (size_t)e * S + 4);
        v[e][0] = a.x; v[e][1] = a.y; v[e][2] = a.z; v[e][3] = a.w;
        v[e][4] = c.x; v[e][5] = c.y; v[e][6] = c.z; v[e][7] = c.w;
    }
    size_t dto = ((size_t)mt * Kt + kt) * 512 + (size_t)lane * 8;
    size_t bstr = (size_t)Mt * Kt * 512;
    for (int bl = 0; bl < 8; bl++) {
        int b = g * 8 + bl;
        float acc[8];
#pragma unroll
        for (int jj = 0; jj < 8; jj++) acc[jj] = 0.f;
#pragma unroll
        for (int e = 0; e < NE; e++) {
            float r = srw[bl * NE + e];
#pragma unroll
            for (int jj = 0; jj < 8; jj++) acc[jj] += r * v[e][jj];
        }
        u16x8 o;
#pragma unroll
        for (int jj = 0; jj < 8; jj++) o[jj] = f2bf_bits(acc[jj]);
        *(u16x8*)(cw + (size_t)b * bstr + dto) = o;
    }
}

// ---------------------------------------------------------------------------
// Combine w2 (fp32 [e][o][i][t9], k = t9*256+i): coalesced tile writes.
// grid = (16*72/4 = 288, 4 groups).
// ---------------------------------------------------------------------------
__global__ __launch_bounds__(256) void combine_w2(
    const float* __restrict__ w2, const float* __restrict__ rw,
    unsigned short* __restrict__ cw) {
    __shared__ float srw[64];
    int tid = threadIdx.x, wv = tid >> 6, lane = tid & 63, ol = lane & 15, g4 = lane >> 4;
    int g = blockIdx.y;
    if (tid < 64) srw[tid] = rw[g * 64 + tid];
    __syncthreads();
    int ot = blockIdx.x / 18, kt = (blockIdx.x - ot * 18) * 4 + wv;
    int t9 = kt >> 3, i0 = (kt & 7) * 32 + g4 * 8;
    int o = ot * 16 + ol;
    const float* src = w2 + ((size_t)o * 256 + i0) * 9 + t9;
    float v[NE][8];
#pragma unroll
    for (int e = 0; e < NE; e++) {
#pragma unroll
        for (int jj = 0; jj < 8; jj++)
            v[e][jj] = src[(size_t)e * S2 + jj * 9];
    }
    size_t dto = ((size_t)ot * 72 + kt) * 512 + (size_t)lane * 8;
    for (int bl = 0; bl < 8; bl++) {
        int b = g * 8 + bl;
        float acc[8];
#pragma unroll
        for (int jj = 0; jj < 8; jj++) acc[jj] = 0.f;
#pragma unroll
        for (int e = 0; e < NE; e++) {
            float r = srw[bl * NE + e];
#pragma unroll
            for (int jj = 0; jj < 8; jj++) acc[jj] += r * v[e][jj];
        }
        u16x8 out;
#pragma unroll
        for (int jj = 0; jj < 8; jj++) out[jj] = f2bf_bits(acc[jj]);
        *(u16x8*)(cw + (size_t)b * (16 * 72 * 512) + dto) = out;
    }
}

// ---------------------------------------------------------------------------
// Generic LDS stage of one k-step: A = 8 m-tiles, B = 7 n-tiles.
// ---------------------------------------------------------------------------
__device__ __forceinline__ void stage_step(
    const unsigned short* Ab, const unsigned short* Bb, int Ktot, int kt,
    unsigned short* lA, unsigned short* lB, int wv, int lane) {
    gl2lds(Ab + ((size_t)wv * Ktot + kt) * 512 + lane * 8, lA + wv * 512, lane);
    gl2lds(Ab + ((size_t)(wv + 4) * Ktot + kt) * 512 + lane * 8, lA + (wv + 4) * 512, lane);
    gl2lds(Bb + ((size_t)wv * Ktot + kt) * 512 + lane * 8, lB + wv * 512, lane);
    if (wv < 3)
        gl2lds(Bb + ((size_t)(4 + wv) * Ktot + kt) * 512 + lane * 8, lB + (4 + wv) * 512, lane);
}

__device__ __forceinline__ void compute_step(
    const unsigned short* lA, const unsigned short* lB,
    f32x4* acc0, f32x4* acc1, int wv, int lane) {
    bf16x8 a0 = *(const bf16x8*)(lA + wv * 512 + lane * 8);
    bf16x8 a1 = *(const bf16x8*)(lA + (wv + 4) * 512 + lane * 8);
#pragma unroll
    for (int t = 0; t < 7; t++) {
        bf16x8 bt = *(const bf16x8*)(lB + t * 512 + lane * 8);
        acc0[t] = __builtin_amdgcn_mfma_f32_16x16x32_bf16(a0, bt, acc0[t], 0, 0, 0);
        acc1[t] = __builtin_amdgcn_mfma_f32_16x16x32_bf16(a1, bt, acc1[t], 0, 0, 0);
    }
}

// ---------------------------------------------------------------------------
// Stage-1 split-K GEMM: 128x112 tile, dbuf x4. grid (BB, 4, 2).
// P[s][b][mt16][nt14][256] fp32 C-fragments.
// ---------------------------------------------------------------------------
__global__ __launch_bounds__(256) void gemm_split(
    const unsigned short* __restrict__ Bsw, const unsigned short* __restrict__ Asw,
    float* __restrict__ P, int Ktot) {
    __shared__ __align__(16) unsigned short lAb[4][8 * 512];
    __shared__ __align__(16) unsigned short lBb[4][7 * 512];
    int b = blockIdx.x, mh = blockIdx.y >> 1, nh = blockIdx.y & 1, s = blockIdx.z;
    int tid = threadIdx.x, wv = tid >> 6, lane = tid & 63;
    int ksteps = Ktot >> 1, kbase = s * ksteps;
    const unsigned short* Ab = Asw + (size_t)(b * 16 + mh * 8) * Ktot * 512;
    const unsigned short* Bb = Bsw + (size_t)(b * 14 + nh * 7) * Ktot * 512;
    f32x4 acc0[7], acc1[7];
#pragma unroll
    for (int t = 0; t < 7; t++) { acc0[t] = {0.f, 0.f, 0.f, 0.f}; acc1[t] = {0.f, 0.f, 0.f, 0.f}; }

    stage_step(Ab, Bb, Ktot, kbase + 0, lAb[0], lBb[0], wv, lane);
    stage_step(Ab, Bb, Ktot, kbase + 1, lAb[1], lBb[1], wv, lane);
    int npair = ksteps >> 1;
    for (int kp = 0; kp < npair; kp++) {
        int cb = (kp & 1) << 1, sb = 2 - cb;
        __syncthreads();
        if (kp + 1 < npair) {
            stage_step(Ab, Bb, Ktot, kbase + 2 * kp + 2, lAb[sb], lBb[sb], wv, lane);
            stage_step(Ab, Bb, Ktot, kbase + 2 * kp + 3, lAb[sb + 1], lBb[sb + 1], wv, lane);
        }
        compute_step(lAb[cb], lBb[cb], acc0, acc1, wv, lane);
        compute_step(lAb[cb + 1], lBb[cb + 1], acc0, acc1, wv, lane);
    }
#pragma unroll
    for (int a = 0; a < 2; a++) {
        int mt = mh * 8 + wv + 4 * a;
#pragma unroll
        for (int t = 0; t < 7; t++) {
            f32x4 v = a ? acc1[t] : acc0[t];
            *(f32x4*)(P + ((((size_t)s * BB + b) * 16 + mt) * 14 + nh * 7 + t) * 256 + lane * 4) = v;
        }
    }
}

// ---------------------------------------------------------------------------
// Stage-2 split-K GEMM with FUSED im2col gather staging: B tiles gathered
// per-lane from swizzled act (zero page for OOB taps) via global_load_lds.
// grid (BB, 4, 4): y = mh*2+nh, z = split s (18 k-tiles each of 72).
// ---------------------------------------------------------------------------
__global__ __launch_bounds__(256) void gemm2_split(
    const unsigned short* __restrict__ act, const unsigned short* __restrict__ cw2,
    const unsigned short* __restrict__ zpad, float* __restrict__ P) {
    __shared__ __align__(16) unsigned short lAb[4][8 * 512];
    __shared__ __align__(16) unsigned short lBb[4][7 * 512];
    int b = blockIdx.x, mh = blockIdx.y >> 1, nh = blockIdx.y & 1, s = blockIdx.z;
    int tid = threadIdx.x, wv = tid >> 6, lane = tid & 63, lo = lane & 15, g4 = lane >> 4;
    const unsigned short* Ab = cw2 + (size_t)(b * 16 + mh * 8) * 72 * 512;
    const unsigned short* actb = act + (size_t)b * 14 * 8 * 512;

    int p0 = (nh * 7 + wv) * 16 + lo;
    int py0 = p0 / HH, px0 = p0 - (p0 / HH) * HH;
    bool pv0 = p0 < HW;
    int p1 = (nh * 7 + wv + 4) * 16 + lo;
    int py1 = p1 / HH, px1 = p1 - (p1 / HH) * HH;
    bool pv1 = (wv < 3) && (p1 < HW);

    f32x4 acc0[7], acc1[7];
#pragma unroll
    for (int t = 0; t < 7; t++) { acc0[t] = {0.f, 0.f, 0.f, 0.f}; acc1[t] = {0.f, 0.f, 0.f, 0.f}; }

    int kbase = s * 18;
    auto stage2 = [&](int kt, unsigned short* lA, unsigned short* lB) {
        gl2lds(Ab + ((size_t)wv * 72 + kt) * 512 + lane * 8, lA + wv * 512, lane);
        gl2lds(Ab + ((size_t)(wv + 4) * 72 + kt) * 512 + lane * 8, lA + (wv + 4) * 512, lane);
        int t9 = kt >> 3;
        int dy = t9 / 3 - 1, dx = t9 - (t9 / 3) * 3 - 1;
        int itile = kt & 7;
        {
            int sy = py0 + dy, sx = px0 + dx;
            bool ok = pv0 && sy >= 0 && sy < HH && sx >= 0 && sx < HH;
            int ns = sy * HH + sx;
            const unsigned short* gp = ok
                ? actb + ((size_t)(ns >> 4) * 8 + itile) * 512 + (size_t)((ns & 15) | (g4 << 4)) * 8
                : zpad;
            gl2lds(gp, lB + wv * 512, lane);
        }
        if (wv < 3) {
            int sy = py1 + dy, sx = px1 + dx;
            bool ok = pv1 && sy >= 0 && sy < HH && sx >= 0 && sx < HH;
            int ns = sy * HH + sx;
            const unsigned short* gp = ok
                ? actb + ((size_t)(ns >> 4) * 8 + itile) * 512 + (size_t)((ns & 15) | (g4 << 4)) * 8
                : zpad;
            gl2lds(gp, lB + (wv + 4) * 512, lane);
        }
    };

    stage2(kbase + 0, lAb[0], lBb[0]);
    stage2(kbase + 1, lAb[1], lBb[1]);
    for (int kp = 0; kp < 9; kp++) {
        int cb = (kp & 1) << 1, sb = 2 - cb;
        __syncthreads();
        if (kp < 8) {
            stage2(kbase + 2 * kp + 2, lAb[sb], lBb[sb]);
            stage2(kbase + 2 * kp + 3, lAb[sb + 1], lBb[sb + 1]);
        }
        compute_step(lAb[cb], lBb[cb], acc0, acc1, wv, lane);
        compute_step(lAb[cb + 1], lBb[cb + 1], acc0, acc1, wv, lane);
    }
#pragma unroll
    for (int a = 0; a < 2; a++) {
        int mt = mh * 8 + wv + 4 * a;
#pragma unroll
        for (int t = 0; t < 7; t++) {
            f32x4 v = a ? acc1[t] : acc0[t];
            *(f32x4*)(P + ((((size_t)s * BB + b) * 16 + mt) * 14 + nh * 7 + t) * 256 + lane * 4) = v;
        }
    }
}

// ---------------------------------------------------------------------------
// Epilogue: sum S partials + BN + ReLU -> swizzled bf16 act + per-channel
// spatial sums. grid (BB, 4).
// ---------------------------------------------------------------------------
__global__ __launch_bounds__(256) void ep12(
    const float* __restrict__ P, int S,
    const float* __restrict__ g, const float* __restrict__ be,
    const float* __restrict__ mu, const float* __restrict__ var,
    unsigned short* __restrict__ actout, float* __restrict__ msum) {
    int b = blockIdx.x;
    int tid = threadIdx.x, wv = tid >> 6, lane = tid & 63, lo = lane & 15, g4 = lane >> 4;
    int mt = blockIdx.y * 4 + wv;
    int c0 = mt * 16 + g4 * 4;
    float sc[4], sh[4];
#pragma unroll
    for (int r = 0; r < 4; r++) {
        float iv = rsqrtf(var[c0 + r] + EPS) * g[c0 + r];
        sc[r] = iv;
        sh[r] = be[c0 + r] - mu[c0 + r] * iv;
    }
    const float* Pb = P + (((size_t)b * 16 + mt) * 14) * 256 + lane * 4;
    size_t pstr = (size_t)BB * 16 * 14 * 256;
    float ms[4] = {0.f, 0.f, 0.f, 0.f};
    int ktc = mt >> 1;
    int lanehi = ((mt * 2 + (g4 >> 1)) & 3) << 4;
    for (int nt = 0; nt < 14; nt++) {
        float v[4] = {0.f, 0.f, 0.f, 0.f};
        for (int s = 0; s < S; s++) {
            f32x4 pv = *(const f32x4*)(Pb + (size_t)s * pstr + (size_t)nt * 256);
#pragma unroll
            for (int r = 0; r < 4; r++) v[r] += pv[r];
        }
        int n = nt * 16 + lo;
#pragma unroll
        for (int r = 0; r < 4; r++) {
            float val = v[r] * sc[r] + sh[r];
            val = fmaxf(val, 0.f);
            if (n >= HW) val = 0.f;
            v[r] = val;
            ms[r] += val;
        }
        unsigned p01 = (unsigned)f2bf_bits(v[0]) | ((unsigned)f2bf_bits(v[1]) << 16);
        unsigned p23 = (unsigned)f2bf_bits(v[2]) | ((unsigned)f2bf_bits(v[3]) << 16);
        size_t off = (((size_t)(b * 14 + nt)) * 8 + ktc) * 512 + (size_t)(lo | lanehi) * 8 + (g4 & 1) * 4;
        *(uint2*)(actout + off) = make_uint2(p01, p23);
    }
#pragma unroll
    for (int r = 0; r < 4; r++) {
        float s = ms[r];
        s += __shfl_xor(s, 1, 64);
        s += __shfl_xor(s, 2, 64);
        s += __shfl_xor(s, 4, 64);
        s += __shfl_xor(s, 8, 64);
        if (lo == 0) msum[b * 256 + c0 + r] = s;
    }
}

// ---------------------------------------------------------------------------
// Stage-3 GEMM, fused BN + fp32 residual + ReLU -> fp32 NCHW. grid (BB, 16).
// ---------------------------------------------------------------------------
__global__ __launch_bounds__(256) void gemm3_fused(
    const unsigned short* __restrict__ Bsw, const unsigned short* __restrict__ Asw,
    const float* __restrict__ g, const float* __restrict__ be,
    const float* __restrict__ mu, const float* __restrict__ var,
    const float* __restrict__ resid, float* __restrict__ out) {
    __shared__ __align__(16) unsigned short lAb[4][8 * 512];
    __shared__ __align__(16) unsigned short lBb[4][7 * 512];
    int b = blockIdx.x, y = blockIdx.y, mh = y >> 1, nh = y & 1;
    int tid = threadIdx.x, wv = tid >> 6, lane = tid & 63, lo = lane & 15, g4 = lane >> 4;
    const unsigned short* Ab = Asw + (size_t)(b * 64 + mh * 8) * 8 * 512;
    const unsigned short* Bb = Bsw + (size_t)(b * 14 + nh * 7) * 8 * 512;
    f32x4 acc0[7], acc1[7];
#pragma unroll
    for (int t = 0; t < 7; t++) { acc0[t] = {0.f, 0.f, 0.f, 0.f}; acc1[t] = {0.f, 0.f, 0.f, 0.f}; }

    stage_step(Ab, Bb, 8, 0, lAb[0], lBb[0], wv, lane);
    stage_step(Ab, Bb, 8, 1, lAb[1], lBb[1], wv, lane);
#pragma unroll
    for (int kp = 0; kp < 4; kp++) {
        int cb = (kp & 1) << 1, sb = 2 - cb;
        __syncthreads();
        if (kp + 1 < 4) {
            stage_step(Ab, Bb, 8, 2 * kp + 2, lAb[sb], lBb[sb], wv, lane);
            stage_step(Ab, Bb, 8, 2 * kp + 3, lAb[sb + 1], lBb[sb + 1], wv, lane);
        }
        compute_step(lAb[cb], lBb[cb], acc0, acc1, wv, lane);
        compute_step(lAb[cb + 1], lBb[cb + 1], acc0, acc1, wv, lane);
    }
#pragma unroll
    for (int a = 0; a < 2; a++) {
        int mt = mh * 8 + wv + 4 * a;
        int c0 = mt * 16 + g4 * 4;
        float sc[4], sh[4];
#pragma unroll
        for (int r = 0; r < 4; r++) {
            float iv = rsqrtf(var[c0 + r] + EPS) * g[c0 + r];
            sc[r] = iv;
            sh[r] = be[c0 + r] - mu[c0 + r] * iv;
        }
#pragma unroll
        for (int t = 0; t < 7; t++) {
            int n = (nh * 7 + t) * 16 + lo;
            if (n >= HW) continue;
            f32x4 av = a ? acc1[t] : acc0[t];
#pragma unroll
            for (int r = 0; r < 4; r++) {
                size_t oidx = ((size_t)(b * OUTP + c0 + r)) * HW + n;
                float val = av[r] * sc[r] + sh[r] + resid[oidx];
                out[oidx] = fmaxf(val, 0.f);
            }
        }
    }
}

// ---------------------------------------------------------------------------
extern "C" void kernel_launch(void* const* d_in, const int* in_sizes, int n_in,
                              void* d_out, int out_size, void* d_ws, size_t ws_size,
                              hipStream_t stream) {
    const float* x    = (const float*)d_in[0];
    const float* w1   = (const float*)d_in[1];
    const float* w2   = (const float*)d_in[2];
    const float* w3   = (const float*)d_in[3];
    const float* r1_w = (const float*)d_in[4];
    const float* r1_b = (const float*)d_in[5];
    const float* r2_w = (const float*)d_in[6];
    const float* r2_b = (const float*)d_in[7];
    const float* r3_w = (const float*)d_in[8];
    const float* r3_b = (const float*)d_in[9];
    const float* bn1_g = (const float*)d_in[10];
    const float* bn1_b = (const float*)d_in[11];
    const float* bn1_m = (const float*)d_in[12];
    const float* bn1_v = (const float*)d_in[13];
    const float* bn2_g = (const float*)d_in[14];
    const float* bn2_b = (const float*)d_in[15];
    const float* bn2_m = (const float*)d_in[16];
    const float* bn2_v = (const float*)d_in[17];
    const float* bn3_g = (const float*)d_in[18];
    const float* bn3_b = (const float*)d_in[19];
    const float* bn3_m = (const float*)d_in[20];
    const float* bn3_v = (const float*)d_in[21];
    float* out = (float*)d_out;

    // Workspace (~87.8 MB).
    //  regionA (31.46 MB): epoch1 xb(14.68)+cw1(16.78); epoch2 P2(29.36);
    //                      epoch3 cw3(16.78).
    char* ws = (char*)d_ws;
    size_t off = 0;
    float* mean1 = (float*)(ws + off); off += (size_t)BB * INP * 4;
    float* msum2 = (float*)(ws + off); off += (size_t)BB * 256 * 4;
    float* msum3 = (float*)(ws + off); off += (size_t)BB * 256 * 4;
    float* rw1 = (float*)(ws + off); off += BB * NE * 4;
    float* rw2 = (float*)(ws + off); off += BB * NE * 4;
    float* rw3 = (float*)(ws + off); off += BB * NE * 4;
    unsigned short* zpad = (unsigned short*)(ws + off); off += 256;
    off = (off + 255) & ~(size_t)255;
    unsigned short* act = (unsigned short*)(ws + off); off += (size_t)BB * 14 * 8 * 512 * 2;   // 3.67 MB
    unsigned short* cw2 = (unsigned short*)(ws + off); off += (size_t)BB * 16 * 72 * 512 * 2;  // 37.75 MB
    float* P1 = (float*)(ws + off); off += (size_t)2 * BB * 16 * 14 * 256 * 4;                 // 14.68 MB
    char* regionA = ws + off; off += (size_t)BB * (14 + 16) * 32 * 512 * 2;                    // 31.46 MB
    unsigned short* xb  = (unsigned short*)regionA;
    unsigned short* cw1 = (unsigned short*)(regionA + (size_t)BB * 14 * 32 * 512 * 2);
    float* P2           = (float*)regionA;            // 29.36 MB (epoch 2)
    unsigned short* cw3 = (unsigned short*)regionA;   // 16.78 MB (epoch 3)
    (void)ws_size;

    hipMemsetAsync(zpad, 0, 256, stream);
    transpose_mean_x<<<dim3(BB, 8), 256, 0, stream>>>(x, xb, mean1);

    // Stage 1: 1x1 conv 1024->256 (split-K2)
    route_kernel<<<BB, 256, 0, stream>>>(mean1, r1_w, r1_b, rw1, INP, 1.0f);
    combine_cont<<<dim3(128, 4), 256, 0, stream>>>(w1, rw1, cw1, S1, 16, 32);
    gemm_split<<<dim3(BB, 4, 2), 256, 0, stream>>>(xb, cw1, P1, 32);
    ep12<<<dim3(BB, 4), 256, 0, stream>>>(P1, 2, bn1_g, bn1_b, bn1_m, bn1_v, act, msum2);

    // Stage 2: 3x3 conv 256->256 (fused-gather split-K4)
    route_kernel<<<BB, 256, 0, stream>>>(msum2, r2_w, r2_b, rw2, WIDTH, 1.0f / (float)HW);
    combine_w2<<<dim3(288, 4), 256, 0, stream>>>(w2, rw2, cw2);
    gemm2_split<<<dim3(BB, 4, 4), 256, 0, stream>>>(act, cw2, zpad, P2);
    ep12<<<dim3(BB, 4), 256, 0, stream>>>(P2, 4, bn2_g, bn2_b, bn2_m, bn2_v, act, msum3);

    // Stage 3: 1x1 conv 256->1024 + residual
    route_kernel<<<BB, 256, 0, stream>>>(msum3, r3_w, r3_b, rw3, WIDTH, 1.0f / (float)HW);
    combine_cont<<<dim3(128, 4), 256, 0, stream>>>(w3, rw3, cw3, S3, 64, 8);
    gemm3_fused<<<dim3(BB, 16), 256, 0, stream>>>(act, cw3, bn3_g, bn3_b, bn3_m, bn3_v, x, out);
}

// Round 7
// 261.376 us; speedup vs baseline: 1.1895x; 1.1895x over previous
//
#include <hip/hip_runtime.h>
#include <hip/hip_bf16.h>

#define BB 32
#define INP 1024
#define WIDTH 256
#define OUTP 1024
#define NE 8
#define HW 196
#define HH 14
#define EPS 1e-5f

#define S1 (WIDTH * INP)        // 262144
#define S2 (WIDTH * WIDTH * 9)  // 589824
#define S3 (OUTP * WIDTH)       // 262144

typedef __attribute__((ext_vector_type(8))) short bf16x8;
typedef __attribute__((ext_vector_type(4))) float f32x4;
typedef __attribute__((ext_vector_type(8))) unsigned short u16x8;

// Swizzled operand layout: tile = 16 rows x 32 k = 512 bf16 = 1 KB.
// Element (r,k) at lane*8 + (k&7), lane = (r&15) | (((k>>3)&3)<<4).
// A wave's MFMA fragment load = tile_base + lane*16B (contiguous 1 KB).

__device__ __forceinline__ unsigned short f2bf_bits(float f) {
    unsigned u = __float_as_uint(f);
    u += 0x7FFFu + ((u >> 16) & 1u);   // RNE
    return (unsigned short)(u >> 16);
}

#if defined(__has_builtin)
#if __has_builtin(__builtin_amdgcn_global_load_lds)
#define HAVE_GLL 1
#endif
#endif
// Async global->LDS: per-lane 16-B source address g; dest = l + lane*16.
__device__ __forceinline__ void gl2lds(const unsigned short* g, unsigned short* l,
                                       int lane) {
#ifdef HAVE_GLL
    __builtin_amdgcn_global_load_lds(
        (const __attribute__((address_space(1))) unsigned int*)(const void*)g,
        (__attribute__((address_space(3))) unsigned int*)(void*)l, 16, 0, 0);
#else
    *(u16x8*)(l + lane * 8) = *(const u16x8*)g;
#endif
}

// ---------------------------------------------------------------------------
// Fused transpose + mean of x: fp32 NCHW -> swizzled bf16 B-operand
// xb[b][nt=14][kt=32][512] + mean1[b][c]. grid (32, 8).
// ---------------------------------------------------------------------------
__global__ __launch_bounds__(256) void transpose_mean_x(
    const float* __restrict__ x, unsigned short* __restrict__ xb,
    float* __restrict__ mean1) {
    __shared__ float lt[128][17];
    int b = blockIdx.x, c0 = blockIdx.y * 128;
    int t = threadIdx.x, cr = t >> 1, half = t & 1;
    const float* src = x + ((size_t)(b * INP + c0 + cr)) * HW;
    float msum = 0.f;
    int j = t >> 4, nl = t & 15;
    for (int pg = 0; pg < 14; pg++) {
        int p0 = pg * 16 + half * 8;
        float vv[8];
        if (pg < 12) {
            float4 a = *(const float4*)(src + p0);
            float4 c = *(const float4*)(src + p0 + 4);
            vv[0] = a.x; vv[1] = a.y; vv[2] = a.z; vv[3] = a.w;
            vv[4] = c.x; vv[5] = c.y; vv[6] = c.z; vv[7] = c.w;
        } else {
#pragma unroll
            for (int i = 0; i < 8; i++) {
                int p = p0 + i;
                vv[i] = (p < HW) ? src[p] : 0.f;
            }
        }
#pragma unroll
        for (int i = 0; i < 8; i++) { msum += vv[i]; lt[cr][half * 8 + i] = vv[i]; }
        __syncthreads();
        unsigned short pk[8];
#pragma unroll
        for (int i = 0; i < 8; i++) pk[i] = f2bf_bits(lt[j * 8 + i][nl]);
        size_t tile = ((size_t)b * 14 + pg) * 32 + (size_t)(blockIdx.y * 4 + (j >> 2));
        int lane = nl | ((j & 3) << 4);
        *(u16x8*)(xb + tile * 512 + lane * 8) = *(u16x8*)pk;
        __syncthreads();
    }
    float other = __shfl_xor(msum, 1, 64);
    if (half == 0) mean1[b * INP + c0 + cr] = (msum + other) * (1.0f / (float)HW);
}

// ---------------------------------------------------------------------------
// Routing: rw[b,e] = sigmoid(scale * (vec[b,:] @ W) + bias). grid = B.
// ---------------------------------------------------------------------------
__global__ __launch_bounds__(256) void route_kernel(const float* __restrict__ mean,
                                                    const float* __restrict__ W,
                                                    const float* __restrict__ bias,
                                                    float* __restrict__ rw, int C,
                                                    float scale) {
    __shared__ float red[NE * 256];
    int b = blockIdx.x, t = threadIdx.x;
    float part[NE];
#pragma unroll
    for (int e = 0; e < NE; e++) part[e] = 0.f;
    for (int c = t; c < C; c += 256) {
        float m = mean[b * C + c];
#pragma unroll
        for (int e = 0; e < NE; e++) part[e] += m * W[c * NE + e];
    }
#pragma unroll
    for (int e = 0; e < NE; e++) red[e * 256 + t] = part[e];
    __syncthreads();
    for (int st = 128; st > 0; st >>= 1) {
        if (t < st) {
#pragma unroll
            for (int e = 0; e < NE; e++) red[e * 256 + t] += red[e * 256 + t + st];
        }
        __syncthreads();
    }
    if (t < NE) {
        float z = red[t * 256] * scale + bias[t];
        rw[b * NE + t] = 1.0f / (1.0f + expf(-z));
    }
}

// ---------------------------------------------------------------------------
// Combine (contiguous-k experts, w1/w3): coalesced tile writes.
// grid = (Mt*Kt/4, 4 sample groups).
// ---------------------------------------------------------------------------
__global__ __launch_bounds__(256) void combine_cont(
    const float* __restrict__ w, const float* __restrict__ rw,
    unsigned short* __restrict__ cw, int S, int Mt, int Kt) {
    __shared__ float srw[64];
    int tid = threadIdx.x, wv = tid >> 6, lane = tid & 63, ml = lane & 15, k8l = lane >> 4;
    int g = blockIdx.y;
    if (tid < 64) srw[tid] = rw[g * 64 + tid];
    __syncthreads();
    int kq = Kt >> 2;
    int mt = blockIdx.x / kq, kt = (blockIdx.x - mt * kq) * 4 + wv;
    int K = Kt * 32;
    const float* src = w + (size_t)(mt * 16 + ml) * K + kt * 32 + k8l * 8;
    float v[NE][8];
#pragma unroll
    for (int e = 0; e < NE; e++) {
        float4 a = *(const float4*)(src + (size_t)e * S);
        float4 c = *(const float4*)(src + (size_t)e * S + 4);
        v[e][0] = a.x; v[e][1] = a.y; v[e][2] = a.z; v[e][3] = a.w;
        v[e][4] = c.x; v[e][5] = c.y; v[e][6] = c.z; v[e][7] = c.w;
    }
    size_t dto = ((size_t)mt * Kt + kt) * 512 + (size_t)lane * 8;
    size_t bstr = (size_t)Mt * Kt * 512;
    for (int bl = 0; bl < 8; bl++) {
        int b = g * 8 + bl;
        float acc[8];
#pragma unroll
        for (int jj = 0; jj < 8; jj++) acc[jj] = 0.f;
#pragma unroll
        for (int e = 0; e < NE; e++) {
            float r = srw[bl * NE + e];
#pragma unroll
            for (int jj = 0; jj < 8; jj++) acc[jj] += r * v[e][jj];
        }
        u16x8 o;
#pragma unroll
        for (int jj = 0; jj < 8; jj++) o[jj] = f2bf_bits(acc[jj]);
        *(u16x8*)(cw + (size_t)b * bstr + dto) = o;
    }
}

// ---------------------------------------------------------------------------
// Permute w2: fp32 [e][o][i][t9] -> bf16 wb2[e][o][k = t9*256+i].
// grid = 2048 (one block per (e,o) row). Reads contiguous (9 fp32/thread,
// threads adjacent), LDS transpose, coalesced u16x8 writes.
// ---------------------------------------------------------------------------
__global__ __launch_bounds__(256) void permute_w2(
    const float* __restrict__ w2, unsigned short* __restrict__ wb2) {
    __shared__ unsigned short lds[9 * 256];
    int eo = blockIdx.x, t = threadIdx.x;
    const float* src = w2 + (size_t)eo * 2304 + (size_t)t * 9;
#pragma unroll
    for (int t9 = 0; t9 < 9; t9++) lds[t9 * 256 + t] = f2bf_bits(src[t9]);
    __syncthreads();
    unsigned short* dst = wb2 + (size_t)eo * 2304;
    for (int j = t; j < 288; j += 256)
        *(u16x8*)(dst + j * 8) = *(const u16x8*)(lds + j * 8);
}

// ---------------------------------------------------------------------------
// Combine w2 from k-ordered bf16 wb2: coalesced 64-B segment reads +
// coalesced tile writes. grid = (288, 4 groups).
// ---------------------------------------------------------------------------
__global__ __launch_bounds__(256) void combine_w2(
    const unsigned short* __restrict__ wb2, const float* __restrict__ rw,
    unsigned short* __restrict__ cw) {
    __shared__ float srw[64];
    int tid = threadIdx.x, wv = tid >> 6, lane = tid & 63, ol = lane & 15, g4 = lane >> 4;
    int g = blockIdx.y;
    if (tid < 64) srw[tid] = rw[g * 64 + tid];
    __syncthreads();
    int ot = blockIdx.x / 18, kt = (blockIdx.x - ot * 18) * 4 + wv;
    const unsigned short* src = wb2 + (size_t)(ot * 16 + ol) * 2304 + kt * 32 + g4 * 8;
    float v[NE][8];
#pragma unroll
    for (int e = 0; e < NE; e++) {
        u16x8 raw = *(const u16x8*)(src + (size_t)e * S2);
#pragma unroll
        for (int jj = 0; jj < 8; jj++)
            v[e][jj] = __uint_as_float((unsigned)raw[jj] << 16);
    }
    size_t dto = ((size_t)ot * 72 + kt) * 512 + (size_t)lane * 8;
    for (int bl = 0; bl < 8; bl++) {
        int b = g * 8 + bl;
        float acc[8];
#pragma unroll
        for (int jj = 0; jj < 8; jj++) acc[jj] = 0.f;
#pragma unroll
        for (int e = 0; e < NE; e++) {
            float r = srw[bl * NE + e];
#pragma unroll
            for (int jj = 0; jj < 8; jj++) acc[jj] += r * v[e][jj];
        }
        u16x8 out;
#pragma unroll
        for (int jj = 0; jj < 8; jj++) out[jj] = f2bf_bits(acc[jj]);
        *(u16x8*)(cw + (size_t)b * (16 * 72 * 512) + dto) = out;
    }
}

// ---------------------------------------------------------------------------
// Generic LDS stage of one k-step: A = 8 m-tiles, B = 7 n-tiles.
// ---------------------------------------------------------------------------
__device__ __forceinline__ void stage_step(
    const unsigned short* Ab, const unsigned short* Bb, int Ktot, int kt,
    unsigned short* lA, unsigned short* lB, int wv, int lane) {
    gl2lds(Ab + ((size_t)wv * Ktot + kt) * 512 + lane * 8, lA + wv * 512, lane);
    gl2lds(Ab + ((size_t)(wv + 4) * Ktot + kt) * 512 + lane * 8, lA + (wv + 4) * 512, lane);
    gl2lds(Bb + ((size_t)wv * Ktot + kt) * 512 + lane * 8, lB + wv * 512, lane);
    if (wv < 3)
        gl2lds(Bb + ((size_t)(4 + wv) * Ktot + kt) * 512 + lane * 8, lB + (4 + wv) * 512, lane);
}

__device__ __forceinline__ void compute_step(
    const unsigned short* lA, const unsigned short* lB,
    f32x4* acc0, f32x4* acc1, int wv, int lane) {
    bf16x8 a0 = *(const bf16x8*)(lA + wv * 512 + lane * 8);
    bf16x8 a1 = *(const bf16x8*)(lA + (wv + 4) * 512 + lane * 8);
#pragma unroll
    for (int t = 0; t < 7; t++) {
        bf16x8 bt = *(const bf16x8*)(lB + t * 512 + lane * 8);
        acc0[t] = __builtin_amdgcn_mfma_f32_16x16x32_bf16(a0, bt, acc0[t], 0, 0, 0);
        acc1[t] = __builtin_amdgcn_mfma_f32_16x16x32_bf16(a1, bt, acc1[t], 0, 0, 0);
    }
}

// ---------------------------------------------------------------------------
// Split-K GEMM (stage 1): 128x112 tile, dbuf x4. grid (BB, 4, S).
// ksteps = Ktot/S. P[s][b][mt16][nt14][256].
// ---------------------------------------------------------------------------
__global__ __launch_bounds__(256) void gemm_split(
    const unsigned short* __restrict__ Bsw, const unsigned short* __restrict__ Asw,
    float* __restrict__ P, int Ktot, int ksteps) {
    __shared__ __align__(16) unsigned short lAb[4][8 * 512];
    __shared__ __align__(16) unsigned short lBb[4][7 * 512];
    int b = blockIdx.x, mh = blockIdx.y >> 1, nh = blockIdx.y & 1, s = blockIdx.z;
    int tid = threadIdx.x, wv = tid >> 6, lane = tid & 63;
    int kbase = s * ksteps;
    const unsigned short* Ab = Asw + (size_t)(b * 16 + mh * 8) * Ktot * 512;
    const unsigned short* Bb = Bsw + (size_t)(b * 14 + nh * 7) * Ktot * 512;
    f32x4 acc0[7], acc1[7];
#pragma unroll
    for (int t = 0; t < 7; t++) { acc0[t] = {0.f, 0.f, 0.f, 0.f}; acc1[t] = {0.f, 0.f, 0.f, 0.f}; }

    stage_step(Ab, Bb, Ktot, kbase + 0, lAb[0], lBb[0], wv, lane);
    stage_step(Ab, Bb, Ktot, kbase + 1, lAb[1], lBb[1], wv, lane);
    int npair = ksteps >> 1;
    for (int kp = 0; kp < npair; kp++) {
        int cb = (kp & 1) << 1, sb = 2 - cb;
        __syncthreads();
        if (kp + 1 < npair) {
            stage_step(Ab, Bb, Ktot, kbase + 2 * kp + 2, lAb[sb], lBb[sb], wv, lane);
            stage_step(Ab, Bb, Ktot, kbase + 2 * kp + 3, lAb[sb + 1], lBb[sb + 1], wv, lane);
        }
        compute_step(lAb[cb], lBb[cb], acc0, acc1, wv, lane);
        compute_step(lAb[cb + 1], lBb[cb + 1], acc0, acc1, wv, lane);
    }
#pragma unroll
    for (int a = 0; a < 2; a++) {
        int mt = mh * 8 + wv + 4 * a;
#pragma unroll
        for (int t = 0; t < 7; t++) {
            f32x4 v = a ? acc1[t] : acc0[t];
            *(f32x4*)(P + ((((size_t)s * BB + b) * 16 + mt) * 14 + nh * 7 + t) * 256 + lane * 4) = v;
        }
    }
}

// ---------------------------------------------------------------------------
// Stage-2 split-K GEMM with fused im2col gather staging. grid (BB, 4, 4).
// ---------------------------------------------------------------------------
__global__ __launch_bounds__(256) void gemm2_split(
    const unsigned short* __restrict__ act, const unsigned short* __restrict__ cw2,
    const unsigned short* __restrict__ zpad, float* __restrict__ P) {
    __shared__ __align__(16) unsigned short lAb[4][8 * 512];
    __shared__ __align__(16) unsigned short lBb[4][7 * 512];
    int b = blockIdx.x, mh = blockIdx.y >> 1, nh = blockIdx.y & 1, s = blockIdx.z;
    int tid = threadIdx.x, wv = tid >> 6, lane = tid & 63, lo = lane & 15, g4 = lane >> 4;
    const unsigned short* Ab = cw2 + (size_t)(b * 16 + mh * 8) * 72 * 512;
    const unsigned short* actb = act + (size_t)b * 14 * 8 * 512;

    int p0 = (nh * 7 + wv) * 16 + lo;
    int py0 = p0 / HH, px0 = p0 - (p0 / HH) * HH;
    bool pv0 = p0 < HW;
    int p1 = (nh * 7 + wv + 4) * 16 + lo;
    int py1 = p1 / HH, px1 = p1 - (p1 / HH) * HH;
    bool pv1 = (wv < 3) && (p1 < HW);

    f32x4 acc0[7], acc1[7];
#pragma unroll
    for (int t = 0; t < 7; t++) { acc0[t] = {0.f, 0.f, 0.f, 0.f}; acc1[t] = {0.f, 0.f, 0.f, 0.f}; }

    int kbase = s * 18;
    auto stage2 = [&](int kt, unsigned short* lA, unsigned short* lB) {
        gl2lds(Ab + ((size_t)wv * 72 + kt) * 512 + lane * 8, lA + wv * 512, lane);
        gl2lds(Ab + ((size_t)(wv + 4) * 72 + kt) * 512 + lane * 8, lA + (wv + 4) * 512, lane);
        int t9 = kt >> 3;
        int dy = t9 / 3 - 1, dx = t9 - (t9 / 3) * 3 - 1;
        int itile = kt & 7;
        {
            int sy = py0 + dy, sx = px0 + dx;
            bool ok = pv0 && sy >= 0 && sy < HH && sx >= 0 && sx < HH;
            int ns = sy * HH + sx;
            const unsigned short* gp = ok
                ? actb + ((size_t)(ns >> 4) * 8 + itile) * 512 + (size_t)((ns & 15) | (g4 << 4)) * 8
                : zpad;
            gl2lds(gp, lB + wv * 512, lane);
        }
        if (wv < 3) {
            int sy = py1 + dy, sx = px1 + dx;
            bool ok = pv1 && sy >= 0 && sy < HH && sx >= 0 && sx < HH;
            int ns = sy * HH + sx;
            const unsigned short* gp = ok
                ? actb + ((size_t)(ns >> 4) * 8 + itile) * 512 + (size_t)((ns & 15) | (g4 << 4)) * 8
                : zpad;
            gl2lds(gp, lB + (wv + 4) * 512, lane);
        }
    };

    stage2(kbase + 0, lAb[0], lBb[0]);
    stage2(kbase + 1, lAb[1], lBb[1]);
    for (int kp = 0; kp < 9; kp++) {
        int cb = (kp & 1) << 1, sb = 2 - cb;
        __syncthreads();
        if (kp < 8) {
            stage2(kbase + 2 * kp + 2, lAb[sb], lBb[sb]);
            stage2(kbase + 2 * kp + 3, lAb[sb + 1], lBb[sb + 1]);
        }
        compute_step(lAb[cb], lBb[cb], acc0, acc1, wv, lane);
        compute_step(lAb[cb + 1], lBb[cb + 1], acc0, acc1, wv, lane);
    }
#pragma unroll
    for (int a = 0; a < 2; a++) {
        int mt = mh * 8 + wv + 4 * a;
#pragma unroll
        for (int t = 0; t < 7; t++) {
            f32x4 v = a ? acc1[t] : acc0[t];
            *(f32x4*)(P + ((((size_t)s * BB + b) * 16 + mt) * 14 + nh * 7 + t) * 256 + lane * 4) = v;
        }
    }
}

// ---------------------------------------------------------------------------
// Epilogue: sum S partials + BN + ReLU -> swizzled bf16 act + per-channel
// spatial sums (atomicAdd; pre-zeroed). grid (BB, 4, 2): z = nt half.
// ---------------------------------------------------------------------------
__global__ __launch_bounds__(256) void ep12(
    const float* __restrict__ P, int S,
    const float* __restrict__ g, const float* __restrict__ be,
    const float* __restrict__ mu, const float* __restrict__ var,
    unsigned short* __restrict__ actout, float* __restrict__ msum) {
    int b = blockIdx.x;
    int tid = threadIdx.x, wv = tid >> 6, lane = tid & 63, lo = lane & 15, g4 = lane >> 4;
    int mt = blockIdx.y * 4 + wv;
    int nt0 = blockIdx.z * 7;
    int c0 = mt * 16 + g4 * 4;
    float sc[4], sh[4];
#pragma unroll
    for (int r = 0; r < 4; r++) {
        float iv = rsqrtf(var[c0 + r] + EPS) * g[c0 + r];
        sc[r] = iv;
        sh[r] = be[c0 + r] - mu[c0 + r] * iv;
    }
    const float* Pb = P + (((size_t)b * 16 + mt) * 14) * 256 + lane * 4;
    size_t pstr = (size_t)BB * 16 * 14 * 256;
    float ms[4] = {0.f, 0.f, 0.f, 0.f};
    int ktc = mt >> 1;
    int lanehi = ((mt * 2 + (g4 >> 1)) & 3) << 4;
    for (int nt = nt0; nt < nt0 + 7; nt++) {
        float v[4] = {0.f, 0.f, 0.f, 0.f};
        for (int s = 0; s < S; s++) {
            f32x4 pv = *(const f32x4*)(Pb + (size_t)s * pstr + (size_t)nt * 256);
#pragma unroll
            for (int r = 0; r < 4; r++) v[r] += pv[r];
        }
        int n = nt * 16 + lo;
#pragma unroll
        for (int r = 0; r < 4; r++) {
            float val = v[r] * sc[r] + sh[r];
            val = fmaxf(val, 0.f);
            if (n >= HW) val = 0.f;
            v[r] = val;
            ms[r] += val;
        }
        unsigned p01 = (unsigned)f2bf_bits(v[0]) | ((unsigned)f2bf_bits(v[1]) << 16);
        unsigned p23 = (unsigned)f2bf_bits(v[2]) | ((unsigned)f2bf_bits(v[3]) << 16);
        size_t off = (((size_t)(b * 14 + nt)) * 8 + ktc) * 512 + (size_t)(lo | lanehi) * 8 + (g4 & 1) * 4;
        *(uint2*)(actout + off) = make_uint2(p01, p23);
    }
#pragma unroll
    for (int r = 0; r < 4; r++) {
        float s = ms[r];
        s += __shfl_xor(s, 1, 64);
        s += __shfl_xor(s, 2, 64);
        s += __shfl_xor(s, 4, 64);
        s += __shfl_xor(s, 8, 64);
        if (lo == 0) atomicAdd(&msum[b * 256 + c0 + r], s);
    }
}

// ---------------------------------------------------------------------------
// Stage-3 GEMM, fused BN + fp32 residual + ReLU -> fp32 NCHW. grid (BB, 16).
// ---------------------------------------------------------------------------
__global__ __launch_bounds__(256) void gemm3_fused(
    const unsigned short* __restrict__ Bsw, const unsigned short* __restrict__ Asw,
    const float* __restrict__ g, const float* __restrict__ be,
    const float* __restrict__ mu, const float* __restrict__ var,
    const float* __restrict__ resid, float* __restrict__ out) {
    __shared__ __align__(16) unsigned short lAb[4][8 * 512];
    __shared__ __align__(16) unsigned short lBb[4][7 * 512];
    int b = blockIdx.x, y = blockIdx.y, mh = y >> 1, nh = y & 1;
    int tid = threadIdx.x, wv = tid >> 6, lane = tid & 63, lo = lane & 15, g4 = lane >> 4;
    const unsigned short* Ab = Asw + (size_t)(b * 64 + mh * 8) * 8 * 512;
    const unsigned short* Bb = Bsw + (size_t)(b * 14 + nh * 7) * 8 * 512;
    f32x4 acc0[7], acc1[7];
#pragma unroll
    for (int t = 0; t < 7; t++) { acc0[t] = {0.f, 0.f, 0.f, 0.f}; acc1[t] = {0.f, 0.f, 0.f, 0.f}; }

    stage_step(Ab, Bb, 8, 0, lAb[0], lBb[0], wv, lane);
    stage_step(Ab, Bb, 8, 1, lAb[1], lBb[1], wv, lane);
#pragma unroll
    for (int kp = 0; kp < 4; kp++) {
        int cb = (kp & 1) << 1, sb = 2 - cb;
        __syncthreads();
        if (kp + 1 < 4) {
            stage_step(Ab, Bb, 8, 2 * kp + 2, lAb[sb], lBb[sb], wv, lane);
            stage_step(Ab, Bb, 8, 2 * kp + 3, lAb[sb + 1], lBb[sb + 1], wv, lane);
        }
        compute_step(lAb[cb], lBb[cb], acc0, acc1, wv, lane);
        compute_step(lAb[cb + 1], lBb[cb + 1], acc0, acc1, wv, lane);
    }
#pragma unroll
    for (int a = 0; a < 2; a++) {
        int mt = mh * 8 + wv + 4 * a;
        int c0 = mt * 16 + g4 * 4;
        float sc[4], sh[4];
#pragma unroll
        for (int r = 0; r < 4; r++) {
            float iv = rsqrtf(var[c0 + r] + EPS) * g[c0 + r];
            sc[r] = iv;
            sh[r] = be[c0 + r] - mu[c0 + r] * iv;
        }
#pragma unroll
        for (int t = 0; t < 7; t++) {
            int n = (nh * 7 + t) * 16 + lo;
            if (n >= HW) continue;
            f32x4 av = a ? acc1[t] : acc0[t];
#pragma unroll
            for (int r = 0; r < 4; r++) {
                size_t oidx = ((size_t)(b * OUTP + c0 + r)) * HW + n;
                float val = av[r] * sc[r] + sh[r] + resid[oidx];
                out[oidx] = fmaxf(val, 0.f);
            }
        }
    }
}

// ---------------------------------------------------------------------------
extern "C" void kernel_launch(void* const* d_in, const int* in_sizes, int n_in,
                              void* d_out, int out_size, void* d_ws, size_t ws_size,
                              hipStream_t stream) {
    const float* x    = (const float*)d_in[0];
    const float* w1   = (const float*)d_in[1];
    const float* w2   = (const float*)d_in[2];
    const float* w3   = (const float*)d_in[3];
    const float* r1_w = (const float*)d_in[4];
    const float* r1_b = (const float*)d_in[5];
    const float* r2_w = (const float*)d_in[6];
    const float* r2_b = (const float*)d_in[7];
    const float* r3_w = (const float*)d_in[8];
    const float* r3_b = (const float*)d_in[9];
    const float* bn1_g = (const float*)d_in[10];
    const float* bn1_b = (const float*)d_in[11];
    const float* bn1_m = (const float*)d_in[12];
    const float* bn1_v = (const float*)d_in[13];
    const float* bn2_g = (const float*)d_in[14];
    const float* bn2_b = (const float*)d_in[15];
    const float* bn2_m = (const float*)d_in[16];
    const float* bn2_v = (const float*)d_in[17];
    const float* bn3_g = (const float*)d_in[18];
    const float* bn3_b = (const float*)d_in[19];
    const float* bn3_m = (const float*)d_in[20];
    const float* bn3_v = (const float*)d_in[21];
    float* out = (float*)d_out;

    // Workspace (~73.2 MB) with time-shared regions:
    //  cw2slot (37.75 MB): epochA P1 [gemm1 -> ep1]; epochB cw2 [combine_w2 -> gemm2]
    //  regionA (31.46 MB): epoch1 xb(14.68)+cw1(16.78) [-> gemm1];
    //                      epoch1.5 wb2(9.44) [permute_w2 -> combine_w2];
    //                      epoch2 P2(29.36) [gemm2 -> ep2]; epoch3 cw3(16.78).
    char* ws = (char*)d_ws;
    size_t off = 0;
    float* mean1 = (float*)(ws + off); off += (size_t)BB * INP * 4;
    float* msum2 = (float*)(ws + off); off += (size_t)BB * 256 * 4;
    float* msum3 = (float*)(ws + off); off += (size_t)BB * 256 * 4;
    float* rw1 = (float*)(ws + off); off += BB * NE * 4;
    float* rw2 = (float*)(ws + off); off += BB * NE * 4;
    float* rw3 = (float*)(ws + off); off += BB * NE * 4;
    unsigned short* zpad = (unsigned short*)(ws + off); off += 256;
    off = (off + 255) & ~(size_t)255;
    unsigned short* act = (unsigned short*)(ws + off); off += (size_t)BB * 14 * 8 * 512 * 2;   // 3.67 MB
    char* cw2slot = ws + off; off += (size_t)BB * 16 * 72 * 512 * 2;                           // 37.75 MB
    float* P1           = (float*)cw2slot;            // 29.36 MB (epoch A, S=4)
    unsigned short* cw2 = (unsigned short*)cw2slot;   // 37.75 MB (epoch B)
    char* regionA = ws + off; off += (size_t)BB * (14 + 16) * 32 * 512 * 2;                    // 31.46 MB
    unsigned short* xb  = (unsigned short*)regionA;
    unsigned short* cw1 = (unsigned short*)(regionA + (size_t)BB * 14 * 32 * 512 * 2);
    unsigned short* wb2 = (unsigned short*)regionA;   // 9.44 MB (epoch 1.5)
    float* P2           = (float*)regionA;            // 29.36 MB (epoch 2)
    unsigned short* cw3 = (unsigned short*)regionA;   // 16.78 MB (epoch 3)
    (void)ws_size;

    hipMemsetAsync(zpad, 0, 256, stream);
    hipMemsetAsync(msum2, 0, (size_t)2 * BB * 256 * 4, stream);
    transpose_mean_x<<<dim3(BB, 8), 256, 0, stream>>>(x, xb, mean1);

    // Stage 1: 1x1 conv 1024->256 (split-K4)
    route_kernel<<<BB, 256, 0, stream>>>(mean1, r1_w, r1_b, rw1, INP, 1.0f);
    combine_cont<<<dim3(128, 4), 256, 0, stream>>>(w1, rw1, cw1, S1, 16, 32);
    gemm_split<<<dim3(BB, 4, 4), 256, 0, stream>>>(xb, cw1, P1, 32, 8);
    permute_w2<<<2048, 256, 0, stream>>>(w2, wb2);   // regionA reuse: xb/cw1 dead
    ep12<<<dim3(BB, 4, 2), 256, 0, stream>>>(P1, 4, bn1_g, bn1_b, bn1_m, bn1_v, act, msum2);

    // Stage 2: 3x3 conv 256->256 (fused-gather split-K4)
    route_kernel<<<BB, 256, 0, stream>>>(msum2, r2_w, r2_b, rw2, WIDTH, 1.0f / (float)HW);
    combine_w2<<<dim3(288, 4), 256, 0, stream>>>(wb2, rw2, cw2);
    gemm2_split<<<dim3(BB, 4, 4), 256, 0, stream>>>(act, cw2, zpad, P2);
    ep12<<<dim3(BB, 4, 2), 256, 0, stream>>>(P2, 4, bn2_g, bn2_b, bn2_m, bn2_v, act, msum3);

    // Stage 3: 1x1 conv 256->1024 + residual
    route_kernel<<<BB, 256, 0, stream>>>(msum3, r3_w, r3_b, rw3, WIDTH, 1.0f / (float)HW);
    combine_cont<<<dim3(128, 4), 256, 0, stream>>>(w3, rw3, cw3, S3, 64, 8);
    gemm3_fused<<<dim3(BB, 16), 256, 0, stream>>>(act, cw3, bn3_g, bn3_b, bn3_m, bn3_v, x, out);
}

// Round 8
// 254.598 us; speedup vs baseline: 1.2211x; 1.0266x over previous
//
#include <hip/hip_runtime.h>
#include <hip/hip_bf16.h>

#define BB 32
#define INP 1024
#define WIDTH 256
#define OUTP 1024
#define NE 8
#define HW 196
#define HH 14
#define EPS 1e-5f

#define S1 (WIDTH * INP)        // 262144
#define S2 (WIDTH * WIDTH * 9)  // 589824
#define S3 (OUTP * WIDTH)       // 262144

typedef __attribute__((ext_vector_type(8))) short bf16x8;
typedef __attribute__((ext_vector_type(4))) float f32x4;
typedef __attribute__((ext_vector_type(8))) unsigned short u16x8;

// Swizzled operand layout: tile = 16 rows x 32 k = 512 bf16 = 1 KB.
// Element (r,k) at lane*8 + (k&7), lane = (r&15) | (((k>>3)&3)<<4).
// A wave's MFMA fragment load = tile_base + lane*16B (contiguous 1 KB).

__device__ __forceinline__ unsigned short f2bf_bits(float f) {
    unsigned u = __float_as_uint(f);
    u += 0x7FFFu + ((u >> 16) & 1u);   // RNE
    return (unsigned short)(u >> 16);
}

#if defined(__has_builtin)
#if __has_builtin(__builtin_amdgcn_global_load_lds)
#define HAVE_GLL 1
#endif
#endif
__device__ __forceinline__ void gl2lds(const unsigned short* g, unsigned short* l,
                                       int lane) {
#ifdef HAVE_GLL
    __builtin_amdgcn_global_load_lds(
        (const __attribute__((address_space(1))) unsigned int*)(const void*)g,
        (__attribute__((address_space(3))) unsigned int*)(void*)l, 16, 0, 0);
#else
    *(u16x8*)(l + lane * 8) = *(const u16x8*)g;
#endif
}

// ---------------------------------------------------------------------------
// In-block routing for an 8-sample group g: srw[s*8+e] =
// sigmoid(scale * (vec[b_s,:] @ W)[e] + bias[e]). Wave wv handles samples
// 2wv, 2wv+1; lane-strided c; butterfly-reduce over 64 lanes.
// ---------------------------------------------------------------------------
__device__ __forceinline__ void block_route(
    const float* __restrict__ vec, const float* __restrict__ W,
    const float* __restrict__ bias, float scale, int C, int g,
    float* srw, int tid) {
    int wv = tid >> 6, lane = tid & 63;
    float p0[NE], p1[NE];
#pragma unroll
    for (int e = 0; e < NE; e++) { p0[e] = 0.f; p1[e] = 0.f; }
    const float* v0 = vec + (size_t)(g * 8 + wv * 2) * C;
    const float* v1 = v0 + C;
    for (int c = lane; c < C; c += 64) {
        float4 wa = *(const float4*)(W + c * 8);
        float4 wb = *(const float4*)(W + c * 8 + 4);
        float m0 = v0[c], m1 = v1[c];
        p0[0] += m0 * wa.x; p0[1] += m0 * wa.y; p0[2] += m0 * wa.z; p0[3] += m0 * wa.w;
        p0[4] += m0 * wb.x; p0[5] += m0 * wb.y; p0[6] += m0 * wb.z; p0[7] += m0 * wb.w;
        p1[0] += m1 * wa.x; p1[1] += m1 * wa.y; p1[2] += m1 * wa.z; p1[3] += m1 * wa.w;
        p1[4] += m1 * wb.x; p1[5] += m1 * wb.y; p1[6] += m1 * wb.z; p1[7] += m1 * wb.w;
    }
#pragma unroll
    for (int j = 1; j < 64; j <<= 1) {
#pragma unroll
        for (int e = 0; e < NE; e++) {
            p0[e] += __shfl_xor(p0[e], j, 64);
            p1[e] += __shfl_xor(p1[e], j, 64);
        }
    }
    if (lane == 0) {
#pragma unroll
        for (int e = 0; e < NE; e++) {
            srw[(wv * 2) * 8 + e] = 1.0f / (1.0f + expf(-(scale * p0[e] + bias[e])));
            srw[(wv * 2 + 1) * 8 + e] = 1.0f / (1.0f + expf(-(scale * p1[e] + bias[e])));
        }
    }
    __syncthreads();
}

// ---------------------------------------------------------------------------
// Fused transpose + mean of x: fp32 NCHW -> swizzled bf16 B-operand
// xb[b][nt=14][kt=32][512] + mean1[b][c]. grid (32, 8).
// ---------------------------------------------------------------------------
__global__ __launch_bounds__(256) void transpose_mean_x(
    const float* __restrict__ x, unsigned short* __restrict__ xb,
    float* __restrict__ mean1) {
    __shared__ float lt[128][17];
    int b = blockIdx.x, c0 = blockIdx.y * 128;
    int t = threadIdx.x, cr = t >> 1, half = t & 1;
    const float* src = x + ((size_t)(b * INP + c0 + cr)) * HW;
    float msum = 0.f;
    int j = t >> 4, nl = t & 15;
    for (int pg = 0; pg < 14; pg++) {
        int p0 = pg * 16 + half * 8;
        float vv[8];
        if (pg < 12) {
            float4 a = *(const float4*)(src + p0);
            float4 c = *(const float4*)(src + p0 + 4);
            vv[0] = a.x; vv[1] = a.y; vv[2] = a.z; vv[3] = a.w;
            vv[4] = c.x; vv[5] = c.y; vv[6] = c.z; vv[7] = c.w;
        } else {
#pragma unroll
            for (int i = 0; i < 8; i++) {
                int p = p0 + i;
                vv[i] = (p < HW) ? src[p] : 0.f;
            }
        }
#pragma unroll
        for (int i = 0; i < 8; i++) { msum += vv[i]; lt[cr][half * 8 + i] = vv[i]; }
        __syncthreads();
        unsigned short pk[8];
#pragma unroll
        for (int i = 0; i < 8; i++) pk[i] = f2bf_bits(lt[j * 8 + i][nl]);
        size_t tile = ((size_t)b * 14 + pg) * 32 + (size_t)(blockIdx.y * 4 + (j >> 2));
        int lane = nl | ((j & 3) << 4);
        *(u16x8*)(xb + tile * 512 + lane * 8) = *(u16x8*)pk;
        __syncthreads();
    }
    float other = __shfl_xor(msum, 1, 64);
    if (half == 0) mean1[b * INP + c0 + cr] = (msum + other) * (1.0f / (float)HW);
}

// ---------------------------------------------------------------------------
// Combine (contiguous-k fp32 experts, w1/w3) + fused routing.
// grid = (Mt*Kt/4, 4 sample groups).
// ---------------------------------------------------------------------------
__global__ __launch_bounds__(256) void combine_cont_r(
    const float* __restrict__ w, const float* __restrict__ vec,
    const float* __restrict__ rW, const float* __restrict__ rB, float scale, int C,
    unsigned short* __restrict__ cw, int S, int Mt, int Kt) {
    __shared__ float srw[64];
    int tid = threadIdx.x, wv = tid >> 6, lane = tid & 63, ml = lane & 15, k8l = lane >> 4;
    int g = blockIdx.y;
    block_route(vec, rW, rB, scale, C, g, srw, tid);
    int kq = Kt >> 2;
    int mt = blockIdx.x / kq, kt = (blockIdx.x - mt * kq) * 4 + wv;
    int K = Kt * 32;
    const float* src = w + (size_t)(mt * 16 + ml) * K + kt * 32 + k8l * 8;
    float v[NE][8];
#pragma unroll
    for (int e = 0; e < NE; e++) {
        float4 a = *(const float4*)(src + (size_t)e * S);
        float4 c = *(const float4*)(src + (size_t)e * S + 4);
        v[e][0] = a.x; v[e][1] = a.y; v[e][2] = a.z; v[e][3] = a.w;
        v[e][4] = c.x; v[e][5] = c.y; v[e][6] = c.z; v[e][7] = c.w;
    }
    size_t dto = ((size_t)mt * Kt + kt) * 512 + (size_t)lane * 8;
    size_t bstr = (size_t)Mt * Kt * 512;
    for (int bl = 0; bl < 8; bl++) {
        int b = g * 8 + bl;
        float acc[8];
#pragma unroll
        for (int jj = 0; jj < 8; jj++) acc[jj] = 0.f;
#pragma unroll
        for (int e = 0; e < NE; e++) {
            float r = srw[bl * NE + e];
#pragma unroll
            for (int jj = 0; jj < 8; jj++) acc[jj] += r * v[e][jj];
        }
        u16x8 o;
#pragma unroll
        for (int jj = 0; jj < 8; jj++) o[jj] = f2bf_bits(acc[jj]);
        *(u16x8*)(cw + (size_t)b * bstr + dto) = o;
    }
}

// ---------------------------------------------------------------------------
// Permute w2: fp32 [e][o][i][t9] -> bf16 wb2[e][o][k = t9*256+i]. grid 2048.
// ---------------------------------------------------------------------------
__global__ __launch_bounds__(256) void permute_w2(
    const float* __restrict__ w2, unsigned short* __restrict__ wb2) {
    __shared__ unsigned short lds[9 * 256];
    int eo = blockIdx.x, t = threadIdx.x;
    const float* src = w2 + (size_t)eo * 2304 + (size_t)t * 9;
#pragma unroll
    for (int t9 = 0; t9 < 9; t9++) lds[t9 * 256 + t] = f2bf_bits(src[t9]);
    __syncthreads();
    unsigned short* dst = wb2 + (size_t)eo * 2304;
    for (int j = t; j < 288; j += 256)
        *(u16x8*)(dst + j * 8) = *(const u16x8*)(lds + j * 8);
}

// ---------------------------------------------------------------------------
// Combine w2 (k-ordered bf16 wb2) + fused routing. grid = (288, 4 groups).
// ---------------------------------------------------------------------------
__global__ __launch_bounds__(256) void combine_w2_r(
    const unsigned short* __restrict__ wb2, const float* __restrict__ vec,
    const float* __restrict__ rW, const float* __restrict__ rB, float scale,
    unsigned short* __restrict__ cw) {
    __shared__ float srw[64];
    int tid = threadIdx.x, wv = tid >> 6, lane = tid & 63, ol = lane & 15, g4 = lane >> 4;
    int g = blockIdx.y;
    block_route(vec, rW, rB, scale, 256, g, srw, tid);
    int ot = blockIdx.x / 18, kt = (blockIdx.x - ot * 18) * 4 + wv;
    const unsigned short* src = wb2 + (size_t)(ot * 16 + ol) * 2304 + kt * 32 + g4 * 8;
    float v[NE][8];
#pragma unroll
    for (int e = 0; e < NE; e++) {
        u16x8 raw = *(const u16x8*)(src + (size_t)e * S2);
#pragma unroll
        for (int jj = 0; jj < 8; jj++)
            v[e][jj] = __uint_as_float((unsigned)raw[jj] << 16);
    }
    size_t dto = ((size_t)ot * 72 + kt) * 512 + (size_t)lane * 8;
    for (int bl = 0; bl < 8; bl++) {
        int b = g * 8 + bl;
        float acc[8];
#pragma unroll
        for (int jj = 0; jj < 8; jj++) acc[jj] = 0.f;
#pragma unroll
        for (int e = 0; e < NE; e++) {
            float r = srw[bl * NE + e];
#pragma unroll
            for (int jj = 0; jj < 8; jj++) acc[jj] += r * v[e][jj];
        }
        u16x8 out;
#pragma unroll
        for (int jj = 0; jj < 8; jj++) out[jj] = f2bf_bits(acc[jj]);
        *(u16x8*)(cw + (size_t)b * (16 * 72 * 512) + dto) = out;
    }
}

// ---------------------------------------------------------------------------
// Fused epilogue (shared): BN + ReLU -> swizzled bf16 act store + per-channel
// spatial-sum atomics. Wave owns m-tile mt x 7 n-tiles (nh half).
// ---------------------------------------------------------------------------
__device__ __forceinline__ void epilogue_act(
    const f32x4* acc, int b, int mt, int nh, int lo, int g4,
    const float* __restrict__ g, const float* __restrict__ be,
    const float* __restrict__ mu, const float* __restrict__ var,
    unsigned short* __restrict__ actout, float* __restrict__ msum) {
    int c0 = mt * 16 + g4 * 4;
    float sc[4], sh[4];
#pragma unroll
    for (int r = 0; r < 4; r++) {
        float iv = rsqrtf(var[c0 + r] + EPS) * g[c0 + r];
        sc[r] = iv;
        sh[r] = be[c0 + r] - mu[c0 + r] * iv;
    }
    float ms[4] = {0.f, 0.f, 0.f, 0.f};
    int ktc = mt >> 1;
    int lanehi = ((mt * 2 + (g4 >> 1)) & 3) << 4;
#pragma unroll
    for (int t = 0; t < 7; t++) {
        int nt = nh * 7 + t;
        int n = nt * 16 + lo;
        float v[4];
#pragma unroll
        for (int r = 0; r < 4; r++) {
            float val = acc[t][r] * sc[r] + sh[r];
            val = fmaxf(val, 0.f);
            if (n >= HW) val = 0.f;
            v[r] = val;
            ms[r] += val;
        }
        unsigned p01 = (unsigned)f2bf_bits(v[0]) | ((unsigned)f2bf_bits(v[1]) << 16);
        unsigned p23 = (unsigned)f2bf_bits(v[2]) | ((unsigned)f2bf_bits(v[3]) << 16);
        size_t off = (((size_t)(b * 14 + nt)) * 8 + ktc) * 512 + (size_t)(lo | lanehi) * 8 + (g4 & 1) * 4;
        *(uint2*)(actout + off) = make_uint2(p01, p23);
    }
#pragma unroll
    for (int r = 0; r < 4; r++) {
        float s = ms[r];
        s += __shfl_xor(s, 1, 64);
        s += __shfl_xor(s, 2, 64);
        s += __shfl_xor(s, 4, 64);
        s += __shfl_xor(s, 8, 64);
        if (lo == 0) atomicAdd(&msum[b * 256 + c0 + r], s);
    }
}

// ---------------------------------------------------------------------------
// Stage-1 fused GEMM: 64x112 tile (wave = 1 m-tile x 7 n-tiles), dbuf x4,
// fused BN/ReLU/act-store/mean. grid (BB, 4, 2): y = mh, z = nh. ksteps=32.
// ---------------------------------------------------------------------------
__global__ __launch_bounds__(256) void gemm1_fused(
    const unsigned short* __restrict__ Bsw, const unsigned short* __restrict__ Asw,
    const float* __restrict__ g, const float* __restrict__ be,
    const float* __restrict__ mu, const float* __restrict__ var,
    unsigned short* __restrict__ actout, float* __restrict__ msum) {
    __shared__ __align__(16) unsigned short lAb[4][4 * 512];
    __shared__ __align__(16) unsigned short lBb[4][7 * 512];
    const int Kt = 32;
    int b = blockIdx.x, mh = blockIdx.y, nh = blockIdx.z;
    int tid = threadIdx.x, wv = tid >> 6, lane = tid & 63, lo = lane & 15, g4 = lane >> 4;
    const unsigned short* Ab = Asw + (size_t)(b * 16 + mh * 4) * Kt * 512;
    const unsigned short* Bb = Bsw + (size_t)(b * 14 + nh * 7) * Kt * 512;
    f32x4 acc[7];
#pragma unroll
    for (int t = 0; t < 7; t++) acc[t] = {0.f, 0.f, 0.f, 0.f};

    auto stage = [&](int kt, unsigned short* lA, unsigned short* lB) {
        gl2lds(Ab + ((size_t)wv * Kt + kt) * 512 + lane * 8, lA + wv * 512, lane);
        gl2lds(Bb + ((size_t)wv * Kt + kt) * 512 + lane * 8, lB + wv * 512, lane);
        if (wv < 3)
            gl2lds(Bb + ((size_t)(4 + wv) * Kt + kt) * 512 + lane * 8, lB + (4 + wv) * 512, lane);
    };
    auto compute = [&](const unsigned short* lA, const unsigned short* lB) {
        bf16x8 a0 = *(const bf16x8*)(lA + wv * 512 + lane * 8);
#pragma unroll
        for (int t = 0; t < 7; t++) {
            bf16x8 bt = *(const bf16x8*)(lB + t * 512 + lane * 8);
            acc[t] = __builtin_amdgcn_mfma_f32_16x16x32_bf16(a0, bt, acc[t], 0, 0, 0);
        }
    };

    stage(0, lAb[0], lBb[0]);
    stage(1, lAb[1], lBb[1]);
    for (int kp = 0; kp < 16; kp++) {
        int cb = (kp & 1) << 1, sb = 2 - cb;
        __syncthreads();
        if (kp < 15) {
            stage(2 * kp + 2, lAb[sb], lBb[sb]);
            stage(2 * kp + 3, lAb[sb + 1], lBb[sb + 1]);
        }
        compute(lAb[cb], lBb[cb]);
        compute(lAb[cb + 1], lBb[cb + 1]);
    }
    epilogue_act(acc, b, mh * 4 + wv, nh, lo, g4, g, be, mu, var, actout, msum);
}

// ---------------------------------------------------------------------------
// Stage-2 fused GEMM with im2col gather staging. grid (BB, 4, 2). ksteps=72.
// ---------------------------------------------------------------------------
__global__ __launch_bounds__(256) void gemm2_fused(
    const unsigned short* __restrict__ act, const unsigned short* __restrict__ cw2,
    const unsigned short* __restrict__ zpad,
    const float* __restrict__ g, const float* __restrict__ be,
    const float* __restrict__ mu, const float* __restrict__ var,
    unsigned short* __restrict__ actout, float* __restrict__ msum) {
    __shared__ __align__(16) unsigned short lAb[4][4 * 512];
    __shared__ __align__(16) unsigned short lBb[4][7 * 512];
    int b = blockIdx.x, mh = blockIdx.y, nh = blockIdx.z;
    int tid = threadIdx.x, wv = tid >> 6, lane = tid & 63, lo = lane & 15, g4 = lane >> 4;
    const unsigned short* Ab = cw2 + (size_t)(b * 16 + mh * 4) * 72 * 512;
    const unsigned short* actb = act + (size_t)b * 14 * 8 * 512;

    int p0 = (nh * 7 + wv) * 16 + lo;
    int py0 = p0 / HH, px0 = p0 - (p0 / HH) * HH;
    bool pv0 = p0 < HW;
    int p1 = (nh * 7 + wv + 4) * 16 + lo;
    int py1 = p1 / HH, px1 = p1 - (p1 / HH) * HH;
    bool pv1 = (wv < 3) && (p1 < HW);

    f32x4 acc[7];
#pragma unroll
    for (int t = 0; t < 7; t++) acc[t] = {0.f, 0.f, 0.f, 0.f};

    auto stage = [&](int kt, unsigned short* lA, unsigned short* lB) {
        gl2lds(Ab + ((size_t)wv * 72 + kt) * 512 + lane * 8, lA + wv * 512, lane);
        int t9 = kt >> 3;
        int dy = t9 / 3 - 1, dx = t9 - (t9 / 3) * 3 - 1;
        int itile = kt & 7;
        {
            int sy = py0 + dy, sx = px0 + dx;
            bool ok = pv0 && sy >= 0 && sy < HH && sx >= 0 && sx < HH;
            int ns = sy * HH + sx;
            const unsigned short* gp = ok
                ? actb + ((size_t)(ns >> 4) * 8 + itile) * 512 + (size_t)((ns & 15) | (g4 << 4)) * 8
                : zpad;
            gl2lds(gp, lB + wv * 512, lane);
        }
        if (wv < 3) {
            int sy = py1 + dy, sx = px1 + dx;
            bool ok = pv1 && sy >= 0 && sy < HH && sx >= 0 && sx < HH;
            int ns = sy * HH + sx;
            const unsigned short* gp = ok
                ? actb + ((size_t)(ns >> 4) * 8 + itile) * 512 + (size_t)((ns & 15) | (g4 << 4)) * 8
                : zpad;
            gl2lds(gp, lB + (wv + 4) * 512, lane);
        }
    };
    auto compute = [&](const unsigned short* lA, const unsigned short* lB) {
        bf16x8 a0 = *(const bf16x8*)(lA + wv * 512 + lane * 8);
#pragma unroll
        for (int t = 0; t < 7; t++) {
            bf16x8 bt = *(const bf16x8*)(lB + t * 512 + lane * 8);
            acc[t] = __builtin_amdgcn_mfma_f32_16x16x32_bf16(a0, bt, acc[t], 0, 0, 0);
        }
    };

    stage(0, lAb[0], lBb[0]);
    stage(1, lAb[1], lBb[1]);
    for (int kp = 0; kp < 36; kp++) {
        int cb = (kp & 1) << 1, sb = 2 - cb;
        __syncthreads();
        if (kp < 35) {
            stage(2 * kp + 2, lAb[sb], lBb[sb]);
            stage(2 * kp + 3, lAb[sb + 1], lBb[sb + 1]);
        }
        compute(lAb[cb], lBb[cb]);
        compute(lAb[cb + 1], lBb[cb + 1]);
    }
    epilogue_act(acc, b, mh * 4 + wv, nh, lo, g4, g, be, mu, var, actout, msum);
}

// ---------------------------------------------------------------------------
// Stage-3 GEMM, fused BN + fp32 residual + ReLU -> fp32 NCHW. grid (BB, 16).
// ---------------------------------------------------------------------------
__global__ __launch_bounds__(256) void gemm3_fused(
    const unsigned short* __restrict__ Bsw, const unsigned short* __restrict__ Asw,
    const float* __restrict__ g, const float* __restrict__ be,
    const float* __restrict__ mu, const float* __restrict__ var,
    const float* __restrict__ resid, float* __restrict__ out) {
    __shared__ __align__(16) unsigned short lAb[4][8 * 512];
    __shared__ __align__(16) unsigned short lBb[4][7 * 512];
    int b = blockIdx.x, y = blockIdx.y, mh = y >> 1, nh = y & 1;
    int tid = threadIdx.x, wv = tid >> 6, lane = tid & 63, lo = lane & 15, g4 = lane >> 4;
    const unsigned short* Ab = Asw + (size_t)(b * 64 + mh * 8) * 8 * 512;
    const unsigned short* Bb = Bsw + (size_t)(b * 14 + nh * 7) * 8 * 512;
    f32x4 acc0[7], acc1[7];
#pragma unroll
    for (int t = 0; t < 7; t++) { acc0[t] = {0.f, 0.f, 0.f, 0.f}; acc1[t] = {0.f, 0.f, 0.f, 0.f}; }

    auto stage = [&](int kt, unsigned short* lA, unsigned short* lB) {
        gl2lds(Ab + ((size_t)wv * 8 + kt) * 512 + lane * 8, lA + wv * 512, lane);
        gl2lds(Ab + ((size_t)(wv + 4) * 8 + kt) * 512 + lane * 8, lA + (wv + 4) * 512, lane);
        gl2lds(Bb + ((size_t)wv * 8 + kt) * 512 + lane * 8, lB + wv * 512, lane);
        if (wv < 3)
            gl2lds(Bb + ((size_t)(4 + wv) * 8 + kt) * 512 + lane * 8, lB + (4 + wv) * 512, lane);
    };
    auto compute = [&](const unsigned short* lA, const unsigned short* lB) {
        bf16x8 a0 = *(const bf16x8*)(lA + wv * 512 + lane * 8);
        bf16x8 a1 = *(const bf16x8*)(lA + (wv + 4) * 512 + lane * 8);
#pragma unroll
        for (int t = 0; t < 7; t++) {
            bf16x8 bt = *(const bf16x8*)(lB + t * 512 + lane * 8);
            acc0[t] = __builtin_amdgcn_mfma_f32_16x16x32_bf16(a0, bt, acc0[t], 0, 0, 0);
            acc1[t] = __builtin_amdgcn_mfma_f32_16x16x32_bf16(a1, bt, acc1[t], 0, 0, 0);
        }
    };

    stage(0, lAb[0], lBb[0]);
    stage(1, lAb[1], lBb[1]);
#pragma unroll
    for (int kp = 0; kp < 4; kp++) {
        int cb = (kp & 1) << 1, sb = 2 - cb;
        __syncthreads();
        if (kp + 1 < 4) {
            stage(2 * kp + 2, lAb[sb], lBb[sb]);
            stage(2 * kp + 3, lAb[sb + 1], lBb[sb + 1]);
        }
        compute(lAb[cb], lBb[cb]);
        compute(lAb[cb + 1], lBb[cb + 1]);
    }
#pragma unroll
    for (int a = 0; a < 2; a++) {
        int mt = mh * 8 + wv + 4 * a;
        int c0 = mt * 16 + g4 * 4;
        float sc[4], sh[4];
#pragma unroll
        for (int r = 0; r < 4; r++) {
            float iv = rsqrtf(var[c0 + r] + EPS) * g[c0 + r];
            sc[r] = iv;
            sh[r] = be[c0 + r] - mu[c0 + r] * iv;
        }
#pragma unroll
        for (int t = 0; t < 7; t++) {
            int n = (nh * 7 + t) * 16 + lo;
            if (n >= HW) continue;
            f32x4 av = a ? acc1[t] : acc0[t];
#pragma unroll
            for (int r = 0; r < 4; r++) {
                size_t oidx = ((size_t)(b * OUTP + c0 + r)) * HW + n;
                float val = av[r] * sc[r] + sh[r] + resid[oidx];
                out[oidx] = fmaxf(val, 0.f);
            }
        }
    }
}

// ---------------------------------------------------------------------------
extern "C" void kernel_launch(void* const* d_in, const int* in_sizes, int n_in,
                              void* d_out, int out_size, void* d_ws, size_t ws_size,
                              hipStream_t stream) {
    const float* x    = (const float*)d_in[0];
    const float* w1   = (const float*)d_in[1];
    const float* w2   = (const float*)d_in[2];
    const float* w3   = (const float*)d_in[3];
    const float* r1_w = (const float*)d_in[4];
    const float* r1_b = (const float*)d_in[5];
    const float* r2_w = (const float*)d_in[6];
    const float* r2_b = (const float*)d_in[7];
    const float* r3_w = (const float*)d_in[8];
    const float* r3_b = (const float*)d_in[9];
    const float* bn1_g = (const float*)d_in[10];
    const float* bn1_b = (const float*)d_in[11];
    const float* bn1_m = (const float*)d_in[12];
    const float* bn1_v = (const float*)d_in[13];
    const float* bn2_g = (const float*)d_in[14];
    const float* bn2_b = (const float*)d_in[15];
    const float* bn2_m = (const float*)d_in[16];
    const float* bn2_v = (const float*)d_in[17];
    const float* bn3_g = (const float*)d_in[18];
    const float* bn3_b = (const float*)d_in[19];
    const float* bn3_m = (const float*)d_in[20];
    const float* bn3_v = (const float*)d_in[21];
    float* out = (float*)d_out;

    // Workspace (~81 MB). regionA (31.46 MB) time-shared:
    //  epoch1 xb(14.68)+cw1(16.78) [-> gemm1]; epoch1.5 wb2(9.44)
    //  [permute_w2 -> combine_w2_r]; epoch3 cw3(16.78) [combine3 -> gemm3].
    char* ws = (char*)d_ws;
    size_t off = 0;
    float* mean1 = (float*)(ws + off); off += (size_t)BB * INP * 4;
    float* msum2 = (float*)(ws + off); off += (size_t)BB * 256 * 4;
    float* msum3 = (float*)(ws + off); off += (size_t)BB * 256 * 4;
    unsigned short* zpad = (unsigned short*)(ws + off); off += 256;
    off = (off + 255) & ~(size_t)255;
    unsigned short* act1 = (unsigned short*)(ws + off); off += (size_t)BB * 14 * 8 * 512 * 2;  // 3.67 MB
    unsigned short* act2 = (unsigned short*)(ws + off); off += (size_t)BB * 14 * 8 * 512 * 2;  // 3.67 MB
    unsigned short* cw2 = (unsigned short*)(ws + off); off += (size_t)BB * 16 * 72 * 512 * 2;  // 37.75 MB
    char* regionA = ws + off; off += (size_t)BB * (14 + 16) * 32 * 512 * 2;                    // 31.46 MB
    unsigned short* xb  = (unsigned short*)regionA;
    unsigned short* cw1 = (unsigned short*)(regionA + (size_t)BB * 14 * 32 * 512 * 2);
    unsigned short* wb2 = (unsigned short*)regionA;   // 9.44 MB (epoch 1.5)
    unsigned short* cw3 = (unsigned short*)regionA;   // 16.78 MB (epoch 3)
    (void)ws_size;

    // Zero msum2+msum3+zpad (contiguous) in one memset.
    hipMemsetAsync(msum2, 0, (size_t)2 * BB * 256 * 4 + 256, stream);
    transpose_mean_x<<<dim3(BB, 8), 256, 0, stream>>>(x, xb, mean1);

    // Stage 1: 1x1 conv 1024->256 (fused route+combine, fused-epilogue GEMM)
    combine_cont_r<<<dim3(128, 4), 256, 0, stream>>>(w1, mean1, r1_w, r1_b, 1.0f, INP,
                                                     cw1, S1, 16, 32);
    gemm1_fused<<<dim3(BB, 4, 2), 256, 0, stream>>>(xb, cw1, bn1_g, bn1_b, bn1_m, bn1_v,
                                                    act1, msum2);
    permute_w2<<<2048, 256, 0, stream>>>(w2, wb2);   // regionA reuse: xb/cw1 dead

    // Stage 2: 3x3 conv 256->256 (gather staging, fused epilogue)
    combine_w2_r<<<dim3(288, 4), 256, 0, stream>>>(wb2, msum2, r2_w, r2_b,
                                                   1.0f / (float)HW, cw2);
    gemm2_fused<<<dim3(BB, 4, 2), 256, 0, stream>>>(act1, cw2, zpad, bn2_g, bn2_b,
                                                    bn2_m, bn2_v, act2, msum3);

    // Stage 3: 1x1 conv 256->1024 + residual
    combine_cont_r<<<dim3(128, 4), 256, 0, stream>>>(w3, msum3, r3_w, r3_b,
                                                     1.0f / (float)HW, WIDTH,
                                                     cw3, S3, 64, 8);
    gemm3_fused<<<dim3(BB, 16), 256, 0, stream>>>(act2, cw3, bn3_g, bn3_b, bn3_m, bn3_v,
                                                  x, out);
}

// Round 9
// 242.165 us; speedup vs baseline: 1.2838x; 1.0513x over previous
//
#include <hip/hip_runtime.h>
#include <hip/hip_bf16.h>

#define BB 32
#define INP 1024
#define WIDTH 256
#define OUTP 1024
#define NE 8
#define HW 196
#define HH 14
#define EPS 1e-5f

#define S1 (WIDTH * INP)        // 262144
#define S2 (WIDTH * WIDTH * 9)  // 589824
#define S3 (OUTP * WIDTH)       // 262144

typedef __attribute__((ext_vector_type(8))) short bf16x8;
typedef __attribute__((ext_vector_type(4))) float f32x4;
typedef __attribute__((ext_vector_type(8))) unsigned short u16x8;

// Swizzled operand layout: tile = 16 rows x 32 k = 512 bf16 = 1 KB.
// Element (r,k) at lane*8 + (k&7), lane = (r&15) | (((k>>3)&3)<<4).

__device__ __forceinline__ unsigned short f2bf_bits(float f) {
    unsigned u = __float_as_uint(f);
    u += 0x7FFFu + ((u >> 16) & 1u);   // RNE
    return (unsigned short)(u >> 16);
}
__device__ __forceinline__ float bf2f(unsigned short h) {
    return __uint_as_float((unsigned)h << 16);
}

#if defined(__has_builtin)
#if __has_builtin(__builtin_amdgcn_global_load_lds)
#define HAVE_GLL 1
#endif
#endif
__device__ __forceinline__ void gl2lds(const unsigned short* g, unsigned short* l,
                                       int lane) {
#ifdef HAVE_GLL
    __builtin_amdgcn_global_load_lds(
        (const __attribute__((address_space(1))) unsigned int*)(const void*)g,
        (__attribute__((address_space(3))) unsigned int*)(void*)l, 16, 0, 0);
#else
    *(u16x8*)(l + lane * 8) = *(const u16x8*)g;
#endif
}

// ---------------------------------------------------------------------------
// In-block routing (8-sample group g): srw[s*8+e] = sigmoid(scale*(v@W)+b).
// First 4 waves only participate meaningfully; block is 256 threads.
// ---------------------------------------------------------------------------
__device__ __forceinline__ void block_route(
    const float* __restrict__ vec, const float* __restrict__ W,
    const float* __restrict__ bias, float scale, int C, int g,
    float* srw, int tid) {
    int wv = tid >> 6, lane = tid & 63;
    float p0[NE], p1[NE];
#pragma unroll
    for (int e = 0; e < NE; e++) { p0[e] = 0.f; p1[e] = 0.f; }
    const float* v0 = vec + (size_t)(g * 8 + wv * 2) * C;
    const float* v1 = v0 + C;
    for (int c = lane; c < C; c += 64) {
        float4 wa = *(const float4*)(W + c * 8);
        float4 wb = *(const float4*)(W + c * 8 + 4);
        float m0 = v0[c], m1 = v1[c];
        p0[0] += m0 * wa.x; p0[1] += m0 * wa.y; p0[2] += m0 * wa.z; p0[3] += m0 * wa.w;
        p0[4] += m0 * wb.x; p0[5] += m0 * wb.y; p0[6] += m0 * wb.z; p0[7] += m0 * wb.w;
        p1[0] += m1 * wa.x; p1[1] += m1 * wa.y; p1[2] += m1 * wa.z; p1[3] += m1 * wa.w;
        p1[4] += m1 * wb.x; p1[5] += m1 * wb.y; p1[6] += m1 * wb.z; p1[7] += m1 * wb.w;
    }
#pragma unroll
    for (int j = 1; j < 64; j <<= 1) {
#pragma unroll
        for (int e = 0; e < NE; e++) {
            p0[e] += __shfl_xor(p0[e], j, 64);
            p1[e] += __shfl_xor(p1[e], j, 64);
        }
    }
    if (lane == 0) {
#pragma unroll
        for (int e = 0; e < NE; e++) {
            srw[(wv * 2) * 8 + e] = 1.0f / (1.0f + expf(-(scale * p0[e] + bias[e])));
            srw[(wv * 2 + 1) * 8 + e] = 1.0f / (1.0f + expf(-(scale * p1[e] + bias[e])));
        }
    }
    __syncthreads();
}

// ---------------------------------------------------------------------------
// Merged pre-kernel. Blocks [0,256): transpose+mean of x -> swizzled xb +
// mean1. Blocks [256,2304): permute w2 -> k-ordered bf16 wb2.
// ---------------------------------------------------------------------------
__global__ __launch_bounds__(256) void pre_kernel(
    const float* __restrict__ x, unsigned short* __restrict__ xb,
    float* __restrict__ mean1,
    const float* __restrict__ w2, unsigned short* __restrict__ wb2) {
    __shared__ __align__(16) char smem[128 * 17 * 4];
    int blk = blockIdx.x, t = threadIdx.x;
    if (blk < 256) {
        float (*lt)[17] = (float(*)[17])smem;
        int b = blk >> 3, yq = blk & 7, c0 = yq * 128;
        int cr = t >> 1, half = t & 1;
        const float* src = x + ((size_t)(b * INP + c0 + cr)) * HW;
        float msum = 0.f;
        int j = t >> 4, nl = t & 15;
        for (int pg = 0; pg < 14; pg++) {
            int p0 = pg * 16 + half * 8;
            float vv[8];
            if (pg < 12) {
                float4 a = *(const float4*)(src + p0);
                float4 c = *(const float4*)(src + p0 + 4);
                vv[0] = a.x; vv[1] = a.y; vv[2] = a.z; vv[3] = a.w;
                vv[4] = c.x; vv[5] = c.y; vv[6] = c.z; vv[7] = c.w;
            } else {
#pragma unroll
                for (int i = 0; i < 8; i++) {
                    int p = p0 + i;
                    vv[i] = (p < HW) ? src[p] : 0.f;
                }
            }
#pragma unroll
            for (int i = 0; i < 8; i++) { msum += vv[i]; lt[cr][half * 8 + i] = vv[i]; }
            __syncthreads();
            unsigned short pk[8];
#pragma unroll
            for (int i = 0; i < 8; i++) pk[i] = f2bf_bits(lt[j * 8 + i][nl]);
            size_t tile = ((size_t)b * 14 + pg) * 32 + (size_t)(yq * 4 + (j >> 2));
            int lane = nl | ((j & 3) << 4);
            *(u16x8*)(xb + tile * 512 + lane * 8) = *(u16x8*)pk;
            __syncthreads();
        }
        float other = __shfl_xor(msum, 1, 64);
        if (half == 0) mean1[b * INP + c0 + cr] = (msum + other) * (1.0f / (float)HW);
    } else {
        unsigned short* lds = (unsigned short*)smem;
        int eo = blk - 256;
        const float* src = w2 + (size_t)eo * 2304 + (size_t)t * 9;
#pragma unroll
        for (int t9 = 0; t9 < 9; t9++) lds[t9 * 256 + t] = f2bf_bits(src[t9]);
        __syncthreads();
        unsigned short* dst = wb2 + (size_t)eo * 2304;
        for (int j = t; j < 288; j += 256)
            *(u16x8*)(dst + j * 8) = *(const u16x8*)(lds + j * 8);
    }
}

// ---------------------------------------------------------------------------
// Combine (contiguous-k fp32 experts, w1/w3) + fused routing.
// grid = (Mt*Kt/4, 4 sample groups), 256 threads.
// ---------------------------------------------------------------------------
__global__ __launch_bounds__(256) void combine_cont_r(
    const float* __restrict__ w, const float* __restrict__ vec,
    const float* __restrict__ rW, const float* __restrict__ rB, float scale, int C,
    unsigned short* __restrict__ cw, int S, int Mt, int Kt) {
    __shared__ float srw[64];
    int tid = threadIdx.x, wv = tid >> 6, lane = tid & 63, ml = lane & 15, k8l = lane >> 4;
    int g = blockIdx.y;
    block_route(vec, rW, rB, scale, C, g, srw, tid);
    int kq = Kt >> 2;
    int mt = blockIdx.x / kq, kt = (blockIdx.x - mt * kq) * 4 + wv;
    int K = Kt * 32;
    const float* src = w + (size_t)(mt * 16 + ml) * K + kt * 32 + k8l * 8;
    float v[NE][8];
#pragma unroll
    for (int e = 0; e < NE; e++) {
        float4 a = *(const float4*)(src + (size_t)e * S);
        float4 c = *(const float4*)(src + (size_t)e * S + 4);
        v[e][0] = a.x; v[e][1] = a.y; v[e][2] = a.z; v[e][3] = a.w;
        v[e][4] = c.x; v[e][5] = c.y; v[e][6] = c.z; v[e][7] = c.w;
    }
    size_t dto = ((size_t)mt * Kt + kt) * 512 + (size_t)lane * 8;
    size_t bstr = (size_t)Mt * Kt * 512;
    for (int bl = 0; bl < 8; bl++) {
        int b = g * 8 + bl;
        float acc[8];
#pragma unroll
        for (int jj = 0; jj < 8; jj++) acc[jj] = 0.f;
#pragma unroll
        for (int e = 0; e < NE; e++) {
            float r = srw[bl * NE + e];
#pragma unroll
            for (int jj = 0; jj < 8; jj++) acc[jj] += r * v[e][jj];
        }
        u16x8 o;
#pragma unroll
        for (int jj = 0; jj < 8; jj++) o[jj] = f2bf_bits(acc[jj]);
        *(u16x8*)(cw + (size_t)b * bstr + dto) = o;
    }
}

// ---------------------------------------------------------------------------
// Combine w2 (k-ordered bf16 wb2) + fused routing. grid = (288, 4 groups).
// ---------------------------------------------------------------------------
__global__ __launch_bounds__(256) void combine_w2_r(
    const unsigned short* __restrict__ wb2, const float* __restrict__ vec,
    const float* __restrict__ rW, const float* __restrict__ rB, float scale,
    unsigned short* __restrict__ cw) {
    __shared__ float srw[64];
    int tid = threadIdx.x, wv = tid >> 6, lane = tid & 63, ol = lane & 15, g4 = lane >> 4;
    int g = blockIdx.y;
    block_route(vec, rW, rB, scale, 256, g, srw, tid);
    int ot = blockIdx.x / 18, kt = (blockIdx.x - ot * 18) * 4 + wv;
    const unsigned short* src = wb2 + (size_t)(ot * 16 + ol) * 2304 + kt * 32 + g4 * 8;
    float v[NE][8];
#pragma unroll
    for (int e = 0; e < NE; e++) {
        u16x8 raw = *(const u16x8*)(src + (size_t)e * S2);
#pragma unroll
        for (int jj = 0; jj < 8; jj++) v[e][jj] = bf2f(raw[jj]);
    }
    size_t dto = ((size_t)ot * 72 + kt) * 512 + (size_t)lane * 8;
    for (int bl = 0; bl < 8; bl++) {
        int b = g * 8 + bl;
        float acc[8];
#pragma unroll
        for (int jj = 0; jj < 8; jj++) acc[jj] = 0.f;
#pragma unroll
        for (int e = 0; e < NE; e++) {
            float r = srw[bl * NE + e];
#pragma unroll
            for (int jj = 0; jj < 8; jj++) acc[jj] += r * v[e][jj];
        }
        u16x8 out;
#pragma unroll
        for (int jj = 0; jj < 8; jj++) out[jj] = f2bf_bits(acc[jj]);
        *(u16x8*)(cw + (size_t)b * (16 * 72 * 512) + dto) = out;
    }
}

// ---------------------------------------------------------------------------
// Fused epilogue: BN + ReLU -> swizzled bf16 act + per-channel sum atomics.
// ---------------------------------------------------------------------------
__device__ __forceinline__ void epilogue_act(
    const f32x4* acc, int b, int mt, int nh, int lo, int g4,
    const float* __restrict__ g, const float* __restrict__ be,
    const float* __restrict__ mu, const float* __restrict__ var,
    unsigned short* __restrict__ actout, float* __restrict__ msum) {
    int c0 = mt * 16 + g4 * 4;
    float sc[4], sh[4];
#pragma unroll
    for (int r = 0; r < 4; r++) {
        float iv = rsqrtf(var[c0 + r] + EPS) * g[c0 + r];
        sc[r] = iv;
        sh[r] = be[c0 + r] - mu[c0 + r] * iv;
    }
    float ms[4] = {0.f, 0.f, 0.f, 0.f};
    int ktc = mt >> 1;
    int lanehi = ((mt * 2 + (g4 >> 1)) & 3) << 4;
#pragma unroll
    for (int t = 0; t < 7; t++) {
        int nt = nh * 7 + t;
        int n = nt * 16 + lo;
        float v[4];
#pragma unroll
        for (int r = 0; r < 4; r++) {
            float val = acc[t][r] * sc[r] + sh[r];
            val = fmaxf(val, 0.f);
            if (n >= HW) val = 0.f;
            v[r] = val;
            ms[r] += val;
        }
        unsigned p01 = (unsigned)f2bf_bits(v[0]) | ((unsigned)f2bf_bits(v[1]) << 16);
        unsigned p23 = (unsigned)f2bf_bits(v[2]) | ((unsigned)f2bf_bits(v[3]) << 16);
        size_t off = (((size_t)(b * 14 + nt)) * 8 + ktc) * 512 + (size_t)(lo | lanehi) * 8 + (g4 & 1) * 4;
        *(uint2*)(actout + off) = make_uint2(p01, p23);
    }
#pragma unroll
    for (int r = 0; r < 4; r++) {
        float s = ms[r];
        s += __shfl_xor(s, 1, 64);
        s += __shfl_xor(s, 2, 64);
        s += __shfl_xor(s, 4, 64);
        s += __shfl_xor(s, 8, 64);
        if (lo == 0) atomicAdd(&msum[b * 256 + c0 + r], s);
    }
}

// ---------------------------------------------------------------------------
// Stage-1 fused GEMM, 512 threads = 8 waves, in-block split-K2:
// group = wave>>2 computes k-steps of parity `group`; partials reduced via
// LDS at the end; group 0 runs the fused epilogue. grid (BB, 4, 2).
// ---------------------------------------------------------------------------
__global__ __launch_bounds__(512) void gemm1_fused(
    const unsigned short* __restrict__ Bsw, const unsigned short* __restrict__ Asw,
    const float* __restrict__ g, const float* __restrict__ be,
    const float* __restrict__ mu, const float* __restrict__ var,
    unsigned short* __restrict__ actout, float* __restrict__ msum) {
    __shared__ __align__(16) unsigned short lAb[4][4 * 512];
    __shared__ __align__(16) unsigned short lBb[4][7 * 512];
    const int Kt = 32;
    int b = blockIdx.x, mh = blockIdx.y, nh = blockIdx.z;
    int tid = threadIdx.x, wv = tid >> 6, grp = wv >> 2, wl = wv & 3;
    int lane = tid & 63, lo = lane & 15, g4 = lane >> 4;
    const unsigned short* Ab = Asw + (size_t)(b * 16 + mh * 4) * Kt * 512;
    const unsigned short* Bb = Bsw + (size_t)(b * 14 + nh * 7) * Kt * 512;
    f32x4 acc[7];
#pragma unroll
    for (int t = 0; t < 7; t++) acc[t] = {0.f, 0.f, 0.f, 0.f};

    auto stage = [&](int kt, unsigned short* lA, unsigned short* lB) {
        gl2lds(Ab + ((size_t)wl * Kt + kt) * 512 + lane * 8, lA + wl * 512, lane);
        gl2lds(Bb + ((size_t)wl * Kt + kt) * 512 + lane * 8, lB + wl * 512, lane);
        if (wl < 3)
            gl2lds(Bb + ((size_t)(4 + wl) * Kt + kt) * 512 + lane * 8, lB + (4 + wl) * 512, lane);
    };
    auto compute = [&](const unsigned short* lA, const unsigned short* lB) {
        bf16x8 a0 = *(const bf16x8*)(lA + wl * 512 + lane * 8);
#pragma unroll
        for (int t = 0; t < 7; t++) {
            bf16x8 bt = *(const bf16x8*)(lB + t * 512 + lane * 8);
            acc[t] = __builtin_amdgcn_mfma_f32_16x16x32_bf16(a0, bt, acc[t], 0, 0, 0);
        }
    };

    // Pre-stage steps 0 (group 0) and 1 (group 1).
    stage(grp, lAb[grp], lBb[grp]);
    for (int kp = 0; kp < 16; kp++) {
        __syncthreads();
        if (kp < 15) {
            int s = 2 * kp + 2 + grp;
            stage(s, lAb[s & 3], lBb[s & 3]);
        }
        int c = (2 * kp + grp) & 3;
        compute(lAb[c], lBb[c]);
    }
    // Cross-group reduction through (dead) B-staging LDS.
    __syncthreads();
    float* red = (float*)&lBb[0][0];   // 4*7*64*4 floats = 28672 B
    if (grp == 1) {
#pragma unroll
        for (int t = 0; t < 7; t++)
            *(f32x4*)(red + (((size_t)wl * 7 + t) * 64 + lane) * 4) = acc[t];
    }
    __syncthreads();
    if (grp == 0) {
#pragma unroll
        for (int t = 0; t < 7; t++) {
            f32x4 o = *(const f32x4*)(red + (((size_t)wl * 7 + t) * 64 + lane) * 4);
#pragma unroll
            for (int r = 0; r < 4; r++) acc[t][r] += o[r];
        }
        epilogue_act(acc, b, mh * 4 + wl, nh, lo, g4, g, be, mu, var, actout, msum);
    }
}

// ---------------------------------------------------------------------------
// Stage-2 fused GEMM (im2col gather staging), 512 threads, in-block split-K2.
// grid (BB, 4, 2). 72 k-steps (9 taps x 8 i-tiles).
// ---------------------------------------------------------------------------
__global__ __launch_bounds__(512) void gemm2_fused(
    const unsigned short* __restrict__ act, const unsigned short* __restrict__ cw2,
    const unsigned short* __restrict__ zpad,
    const float* __restrict__ g, const float* __restrict__ be,
    const float* __restrict__ mu, const float* __restrict__ var,
    unsigned short* __restrict__ actout, float* __restrict__ msum) {
    __shared__ __align__(16) unsigned short lAb[4][4 * 512];
    __shared__ __align__(16) unsigned short lBb[4][7 * 512];
    int b = blockIdx.x, mh = blockIdx.y, nh = blockIdx.z;
    int tid = threadIdx.x, wv = tid >> 6, grp = wv >> 2, wl = wv & 3;
    int lane = tid & 63, lo = lane & 15, g4 = lane >> 4;
    const unsigned short* Ab = cw2 + (size_t)(b * 16 + mh * 4) * 72 * 512;
    const unsigned short* actb = act + (size_t)b * 14 * 8 * 512;

    int p0 = (nh * 7 + wl) * 16 + lo;
    int py0 = p0 / HH, px0 = p0 - (p0 / HH) * HH;
    bool pv0 = p0 < HW;
    int p1 = (nh * 7 + wl + 4) * 16 + lo;
    int py1 = p1 / HH, px1 = p1 - (p1 / HH) * HH;
    bool pv1 = (wl < 3) && (p1 < HW);

    f32x4 acc[7];
#pragma unroll
    for (int t = 0; t < 7; t++) acc[t] = {0.f, 0.f, 0.f, 0.f};

    auto stage = [&](int kt, unsigned short* lA, unsigned short* lB) {
        gl2lds(Ab + ((size_t)wl * 72 + kt) * 512 + lane * 8, lA + wl * 512, lane);
        int t9 = kt >> 3;
        int dy = t9 / 3 - 1, dx = t9 - (t9 / 3) * 3 - 1;
        int itile = kt & 7;
        {
            int sy = py0 + dy, sx = px0 + dx;
            bool ok = pv0 && sy >= 0 && sy < HH && sx >= 0 && sx < HH;
            int ns = sy * HH + sx;
            const unsigned short* gp = ok
                ? actb + ((size_t)(ns >> 4) * 8 + itile) * 512 + (size_t)((ns & 15) | (g4 << 4)) * 8
                : zpad;
            gl2lds(gp, lB + wl * 512, lane);
        }
        if (wl < 3) {
            int sy = py1 + dy, sx = px1 + dx;
            bool ok = pv1 && sy >= 0 && sy < HH && sx >= 0 && sx < HH;
            int ns = sy * HH + sx;
            const unsigned short* gp = ok
                ? actb + ((size_t)(ns >> 4) * 8 + itile) * 512 + (size_t)((ns & 15) | (g4 << 4)) * 8
                : zpad;
            gl2lds(gp, lB + (wl + 4) * 512, lane);
        }
    };
    auto compute = [&](const unsigned short* lA, const unsigned short* lB) {
        bf16x8 a0 = *(const bf16x8*)(lA + wl * 512 + lane * 8);
#pragma unroll
        for (int t = 0; t < 7; t++) {
            bf16x8 bt = *(const bf16x8*)(lB + t * 512 + lane * 8);
            acc[t] = __builtin_amdgcn_mfma_f32_16x16x32_bf16(a0, bt, acc[t], 0, 0, 0);
        }
    };

    stage(grp, lAb[grp], lBb[grp]);
    for (int kp = 0; kp < 36; kp++) {
        __syncthreads();
        if (kp < 35) {
            int s = 2 * kp + 2 + grp;
            stage(s, lAb[s & 3], lBb[s & 3]);
        }
        int c = (2 * kp + grp) & 3;
        compute(lAb[c], lBb[c]);
    }
    __syncthreads();
    float* red = (float*)&lBb[0][0];
    if (grp == 1) {
#pragma unroll
        for (int t = 0; t < 7; t++)
            *(f32x4*)(red + (((size_t)wl * 7 + t) * 64 + lane) * 4) = acc[t];
    }
    __syncthreads();
    if (grp == 0) {
#pragma unroll
        for (int t = 0; t < 7; t++) {
            f32x4 o = *(const f32x4*)(red + (((size_t)wl * 7 + t) * 64 + lane) * 4);
#pragma unroll
            for (int r = 0; r < 4; r++) acc[t][r] += o[r];
        }
        epilogue_act(acc, b, mh * 4 + wl, nh, lo, g4, g, be, mu, var, actout, msum);
    }
}

// ---------------------------------------------------------------------------
// Stage-3 GEMM, 512 threads, in-block split-K2, fused BN + bf16 residual
// (from swizzled xb) + ReLU -> fp32 NCHW. grid (BB, 16). K=256 (8 steps).
// ---------------------------------------------------------------------------
__global__ __launch_bounds__(512) void gemm3_fused(
    const unsigned short* __restrict__ Bsw, const unsigned short* __restrict__ Asw,
    const float* __restrict__ g, const float* __restrict__ be,
    const float* __restrict__ mu, const float* __restrict__ var,
    const unsigned short* __restrict__ xb, float* __restrict__ out) {
    __shared__ __align__(16) unsigned short lAb[4][8 * 512];
    __shared__ __align__(16) unsigned short lBb[4][7 * 512];
    int b = blockIdx.x, y = blockIdx.y, mh = y >> 1, nh = y & 1;
    int tid = threadIdx.x, wv = tid >> 6, grp = wv >> 2, wl = wv & 3;
    int lane = tid & 63, lo = lane & 15, g4 = lane >> 4;
    const unsigned short* Ab = Asw + (size_t)(b * 64 + mh * 8) * 8 * 512;
    const unsigned short* Bb = Bsw + (size_t)(b * 14 + nh * 7) * 8 * 512;
    f32x4 acc0[7], acc1[7];
#pragma unroll
    for (int t = 0; t < 7; t++) { acc0[t] = {0.f, 0.f, 0.f, 0.f}; acc1[t] = {0.f, 0.f, 0.f, 0.f}; }

    auto stage = [&](int kt, unsigned short* lA, unsigned short* lB) {
        gl2lds(Ab + ((size_t)wl * 8 + kt) * 512 + lane * 8, lA + wl * 512, lane);
        gl2lds(Ab + ((size_t)(wl + 4) * 8 + kt) * 512 + lane * 8, lA + (wl + 4) * 512, lane);
        gl2lds(Bb + ((size_t)wl * 8 + kt) * 512 + lane * 8, lB + wl * 512, lane);
        if (wl < 3)
            gl2lds(Bb + ((size_t)(4 + wl) * 8 + kt) * 512 + lane * 8, lB + (4 + wl) * 512, lane);
    };
    auto compute = [&](const unsigned short* lA, const unsigned short* lB) {
        bf16x8 a0 = *(const bf16x8*)(lA + wl * 512 + lane * 8);
        bf16x8 a1 = *(const bf16x8*)(lA + (wl + 4) * 512 + lane * 8);
#pragma unroll
        for (int t = 0; t < 7; t++) {
            bf16x8 bt = *(const bf16x8*)(lB + t * 512 + lane * 8);
            acc0[t] = __builtin_amdgcn_mfma_f32_16x16x32_bf16(a0, bt, acc0[t], 0, 0, 0);
            acc1[t] = __builtin_amdgcn_mfma_f32_16x16x32_bf16(a1, bt, acc1[t], 0, 0, 0);
        }
    };

    stage(grp, lAb[grp], lBb[grp]);
    for (int kp = 0; kp < 4; kp++) {
        __syncthreads();
        if (kp < 3) {
            int s = 2 * kp + 2 + grp;
            stage(s, lAb[s & 3], lBb[s & 3]);
        }
        int c = (2 * kp + grp) & 3;
        compute(lAb[c], lBb[c]);
    }
    // Two-phase cross-group reduction via lBb (28672 B per phase).
    __syncthreads();
    float* red = (float*)&lBb[0][0];
    if (grp == 1) {
#pragma unroll
        for (int t = 0; t < 7; t++)
            *(f32x4*)(red + (((size_t)wl * 7 + t) * 64 + lane) * 4) = acc0[t];
    }
    __syncthreads();
    if (grp == 0) {
#pragma unroll
        for (int t = 0; t < 7; t++) {
            f32x4 o = *(const f32x4*)(red + (((size_t)wl * 7 + t) * 64 + lane) * 4);
#pragma unroll
            for (int r = 0; r < 4; r++) acc0[t][r] += o[r];
        }
    }
    __syncthreads();
    if (grp == 1) {
#pragma unroll
        for (int t = 0; t < 7; t++)
            *(f32x4*)(red + (((size_t)wl * 7 + t) * 64 + lane) * 4) = acc1[t];
    }
    __syncthreads();
    if (grp != 0) return;
#pragma unroll
    for (int t = 0; t < 7; t++) {
        f32x4 o = *(const f32x4*)(red + (((size_t)wl * 7 + t) * 64 + lane) * 4);
#pragma unroll
        for (int r = 0; r < 4; r++) acc1[t][r] += o[r];
    }

#pragma unroll
    for (int a = 0; a < 2; a++) {
        int mt = mh * 8 + wl + 4 * a;
        int c0 = mt * 16 + g4 * 4;
        float sc[4], sh[4];
#pragma unroll
        for (int r = 0; r < 4; r++) {
            float iv = rsqrtf(var[c0 + r] + EPS) * g[c0 + r];
            sc[r] = iv;
            sh[r] = be[c0 + r] - mu[c0 + r] * iv;
        }
        int ktc = mt >> 1;
        int lanehi = ((mt * 2 + (g4 >> 1)) & 3) << 4;
#pragma unroll
        for (int t = 0; t < 7; t++) {
            int nt = nh * 7 + t;
            int n = nt * 16 + lo;
            if (n >= HW) continue;
            // bf16 residual from swizzled xb (K-tiles of 32 over c=0..1023).
            const unsigned short* xr = xb + (((size_t)(b * 14 + nt)) * 32 + ktc) * 512
                                       + (size_t)(lo | lanehi) * 8 + (g4 & 1) * 4;
            uint2 rv = *(const uint2*)xr;
            float res[4] = {bf2f((unsigned short)(rv.x & 0xffff)),
                            bf2f((unsigned short)(rv.x >> 16)),
                            bf2f((unsigned short)(rv.y & 0xffff)),
                            bf2f((unsigned short)(rv.y >> 16))};
            f32x4 av = a ? acc1[t] : acc0[t];
#pragma unroll
            for (int r = 0; r < 4; r++) {
                size_t oidx = ((size_t)(b * OUTP + c0 + r)) * HW + n;
                float val = av[r] * sc[r] + sh[r] + res[r];
                out[oidx] = fmaxf(val, 0.f);
            }
        }
    }
}

// ---------------------------------------------------------------------------
extern "C" void kernel_launch(void* const* d_in, const int* in_sizes, int n_in,
                              void* d_out, int out_size, void* d_ws, size_t ws_size,
                              hipStream_t stream) {
    const float* x    = (const float*)d_in[0];
    const float* w1   = (const float*)d_in[1];
    const float* w2   = (const float*)d_in[2];
    const float* w3   = (const float*)d_in[3];
    const float* r1_w = (const float*)d_in[4];
    const float* r1_b = (const float*)d_in[5];
    const float* r2_w = (const float*)d_in[6];
    const float* r2_b = (const float*)d_in[7];
    const float* r3_w = (const float*)d_in[8];
    const float* r3_b = (const float*)d_in[9];
    const float* bn1_g = (const float*)d_in[10];
    const float* bn1_b = (const float*)d_in[11];
    const float* bn1_m = (const float*)d_in[12];
    const float* bn1_v = (const float*)d_in[13];
    const float* bn2_g = (const float*)d_in[14];
    const float* bn2_b = (const float*)d_in[15];
    const float* bn2_m = (const float*)d_in[16];
    const float* bn2_v = (const float*)d_in[17];
    const float* bn3_g = (const float*)d_in[18];
    const float* bn3_b = (const float*)d_in[19];
    const float* bn3_m = (const float*)d_in[20];
    const float* bn3_v = (const float*)d_in[21];
    float* out = (float*)d_out;

    // Workspace (~86.4 MB). cwX slot time-shared: cw1 (stage 1) then cw3
    // (stage 3; cw1 dead after gemm1). xb persists to gemm3 (bf16 residual).
    char* ws = (char*)d_ws;
    size_t off = 0;
    float* mean1 = (float*)(ws + off); off += (size_t)BB * INP * 4;
    float* msum2 = (float*)(ws + off); off += (size_t)BB * 256 * 4;
    float* msum3 = (float*)(ws + off); off += (size_t)BB * 256 * 4;
    unsigned short* zpad = (unsigned short*)(ws + off); off += 256;
    off = (off + 255) & ~(size_t)255;
    unsigned short* act1 = (unsigned short*)(ws + off); off += (size_t)BB * 14 * 8 * 512 * 2;  // 3.67 MB
    unsigned short* act2 = (unsigned short*)(ws + off); off += (size_t)BB * 14 * 8 * 512 * 2;  // 3.67 MB
    unsigned short* cw2 = (unsigned short*)(ws + off); off += (size_t)BB * 16 * 72 * 512 * 2;  // 37.75 MB
    unsigned short* xb  = (unsigned short*)(ws + off); off += (size_t)BB * 14 * 32 * 512 * 2;  // 14.68 MB
    unsigned short* wb2 = (unsigned short*)(ws + off); off += (size_t)S2 * NE * 2;             // 9.44 MB
    unsigned short* cwX = (unsigned short*)(ws + off); off += (size_t)BB * S1 * 2;             // 16.78 MB
    unsigned short* cw1 = cwX;
    unsigned short* cw3 = cwX;
    (void)ws_size;

    // Zero msum2+msum3+zpad (contiguous) in one memset.
    hipMemsetAsync(msum2, 0, (size_t)2 * BB * 256 * 4 + 256, stream);

    // Pre: transpose+mean of x (blocks 0-255) || permute w2 (blocks 256-2303).
    pre_kernel<<<2304, 256, 0, stream>>>(x, xb, mean1, w2, wb2);

    // Stage 1: 1x1 conv 1024->256
    combine_cont_r<<<dim3(128, 4), 256, 0, stream>>>(w1, mean1, r1_w, r1_b, 1.0f, INP,
                                                     cw1, S1, 16, 32);
    gemm1_fused<<<dim3(BB, 4, 2), 512, 0, stream>>>(xb, cw1, bn1_g, bn1_b, bn1_m, bn1_v,
                                                    act1, msum2);

    // Stage 2: 3x3 conv 256->256
    combine_w2_r<<<dim3(288, 4), 256, 0, stream>>>(wb2, msum2, r2_w, r2_b,
                                                   1.0f / (float)HW, cw2);
    gemm2_fused<<<dim3(BB, 4, 2), 512, 0, stream>>>(act1, cw2, zpad, bn2_g, bn2_b,
                                                    bn2_m, bn2_v, act2, msum3);

    // Stage 3: 1x1 conv 256->1024 + residual
    combine_cont_r<<<dim3(128, 4), 256, 0, stream>>>(w3, msum3, r3_w, r3_b,
                                                     1.0f / (float)HW, WIDTH,
                                                     cw3, S3, 64, 8);
    gemm3_fused<<<dim3(BB, 16), 512, 0, stream>>>(act2, cw3, bn3_g, bn3_b, bn3_m, bn3_v,
                                                  xb, out);
}